// Round 2
// baseline (1090.846 us; speedup 1.0000x reference)
//
#include <hip/hip_runtime.h>
#include <stdint.h>

// Problem constants
#define NROWS 16384   // B*H*W = 16*32*32
#define KENT  8192    // codebook entries
#define CDIM  256     // embedding dim
#define NELEM 4194304 // B*H*W*C elements of z / z_q

// Tiling for the score kernel
#define TM 128        // z-rows per block
#define TK 128        // codebook entries per block
#define CCH 32        // C-chunk

// ws layout (bytes):
//   [0,      131072): packed u64 per row (atomicMin targets) -- memset 0xFF
//   [131072, 196608): z2 per row (16384 floats, np-pairwise-replicated)
//   [196608, 262144): final indices (16384 ints)
// loss accumulates directly into out[NELEM] (memset 0 in launch).

// ---------------------------------------------------------------------------
// z2[n] = sum(z_flat[n]^2) replicating numpy AVX512 pairwise summation EXACTLY:
// n=256 -> two 128-blocks. Block: 8 zmm "accumulators" r_j = a[16j+L] (one
// load each), combined ((r0+r1)+(r2+r3))+((r4+r5)+(r6+r7)) per lane L, then
// _mm512_reduce_add_ps halving tree over lanes (dist 8,4,2,1). z2 = blk0+blk1.
// Products z*z are rounded separately (asm barrier blocks FMA contraction).
__global__ __launch_bounds__(256) void vq_z2(const float* __restrict__ z,
                                             float* __restrict__ z2w) {
    int n = blockIdx.x * 256 + threadIdx.x;
    int b = n >> 10, hw = n & 1023;
    const float* base = z + b * 262144 + hw;   // element c at base[c*1024]
    float bs[2];
#pragma unroll
    for (int blk = 0; blk < 2; ++blk) {
        float C[16];
#pragma unroll
        for (int L = 0; L < 16; ++L) {
            float q[8];
#pragma unroll
            for (int j = 0; j < 8; ++j) {
                float a = base[(blk * 128 + L + 16 * j) * 1024];
                float sq = a * a;
                asm volatile("" : "+v"(sq));   // force separate rounding (no FMA fuse)
                q[j] = sq;
            }
            C[L] = ((q[0] + q[1]) + (q[2] + q[3])) + ((q[4] + q[5]) + (q[6] + q[7]));
        }
        float t8[8];
#pragma unroll
        for (int L = 0; L < 8; ++L) t8[L] = C[L] + C[L + 8];
        float t4[4];
#pragma unroll
        for (int L = 0; L < 4; ++L) t4[L] = t8[L] + t8[L + 4];
        float t2a = t4[0] + t4[2];
        float t2b = t4[1] + t4[3];
        bs[blk] = t2a + t2b;
    }
    z2w[n] = bs[0] + bs[1];
}

// ---------------------------------------------------------------------------
// Exact-replication score kernel:
//   s_k = sequential fp32 FMA chain over c=0..255 (BLAS sgemm order)
//   d_k = fl(z2 - 2*s_k)      (e2 provably absorbed: e2 < ulp(z2)/2)
//   argmin with ties -> lowest k, via atomicMin on (d_bits<<32 | k).
// Block: 256 threads as 16x16; thread tile 8 rows x 8 cols.
__global__ __launch_bounds__(256, 3) void vq_scores(
        const float* __restrict__ z, const float* __restrict__ cb,
        const float* __restrict__ z2w, unsigned long long* __restrict__ packed) {
    __shared__ float zs[CCH][TM];      // [c][r]
    __shared__ float es[CCH][132];     // [c][k], stride 132 breaks conflicts
    __shared__ float z2s[TM];

    const int t  = threadIdx.x;
    const int tx = t & 15, ty = t >> 4;
    const int k0 = blockIdx.x * TK;
    const int n0 = blockIdx.y * TM;

    const int b   = n0 >> 10;
    const int hw0 = n0 & 1023;
    const float* zbase = z + b * 262144 + hw0;

    if (t < TM) z2s[t] = z2w[n0 + t];

    float acc[8][8];
#pragma unroll
    for (int i = 0; i < 8; ++i)
#pragma unroll
        for (int j = 0; j < 8; ++j) acc[i][j] = 0.f;

    for (int c0 = 0; c0 < CDIM; c0 += CCH) {
        __syncthreads();
        {   // z chunk: zs[c][r]; lanes walk w => coalesced
            const int r = t & 127;
            const int cb0 = t >> 7; // 0 or 1
#pragma unroll
            for (int it = 0; it < 16; ++it) {
                int c = cb0 + it * 2;
                zs[c][r] = zbase[(c0 + c) * 1024 + r];
            }
        }
        {   // e chunk: es[c][k]; float4 along contiguous c
            const int cc = (t & 7) * 4;
            const int kk = t >> 3;
#pragma unroll
            for (int it = 0; it < 4; ++it) {
                int k = kk + it * 32;
                float4 v = *(const float4*)&cb[(k0 + k) * CDIM + c0 + cc];
                es[cc + 0][k] = v.x;
                es[cc + 1][k] = v.y;
                es[cc + 2][k] = v.z;
                es[cc + 3][k] = v.w;
            }
        }
        __syncthreads();

#pragma unroll
        for (int c = 0; c < CCH; ++c) {
            float4 zA = *(const float4*)&zs[c][ty * 8];
            float4 zB = *(const float4*)&zs[c][ty * 8 + 4];
            float4 eA = *(const float4*)&es[c][tx * 4];
            float4 eB = *(const float4*)&es[c][64 + tx * 4];
            float zr[8] = {zA.x, zA.y, zA.z, zA.w, zB.x, zB.y, zB.z, zB.w};
            float ek[8] = {eA.x, eA.y, eA.z, eA.w, eB.x, eB.y, eB.z, eB.w};
#pragma unroll
            for (int i = 0; i < 8; ++i)
#pragma unroll
                for (int j = 0; j < 8; ++j)
                    acc[i][j] = __builtin_fmaf(zr[i], ek[j], acc[i][j]);
        }
    }

#pragma unroll
    for (int i = 0; i < 8; ++i) {
        const int r = ty * 8 + i;
        const float z2v = z2s[r];
        unsigned long long key = 0xFFFFFFFFFFFFFFFFull;
#pragma unroll
        for (int j = 0; j < 8; ++j) {
            int klocal = (j < 4) ? (tx * 4 + j) : (64 + tx * 4 + (j - 4));
            float d = z2v - 2.0f * acc[i][j];   // single-rounded; d > 0 always
            unsigned long long cand =
                ((unsigned long long)__float_as_uint(d) << 32) |
                (unsigned int)(k0 + klocal);
            if (cand < key) key = cand;
        }
#pragma unroll
        for (int off = 1; off < 16; off <<= 1) {
            unsigned long long other = __shfl_xor(key, off, 64);
            if (other < key) key = other;
        }
        if (tx == 0) atomicMin(&packed[n0 + r], key);
    }
}

// ---------------------------------------------------------------------------
__global__ void vq_finalize_idx(const unsigned long long* __restrict__ packed,
                                int* __restrict__ idx, float* __restrict__ out_idx) {
    int n = blockIdx.x * 256 + threadIdx.x;
    int k = (int)(unsigned int)(packed[n] & 0xFFFFFFFFu);
    idx[n] = k;
    out_idx[n] = (float)k;
}

// ---------------------------------------------------------------------------
// z_q scatter in OUTPUT order (coalesced store) + fused loss accumulation.
// out[b,i,j,k] = cb[idx[b*1024 + j*32 + (k>>3)]][(k&7)*32 + i]
// zp[b,i,j,k] = z[b,k,i,j];  loss = 1.25*mean((zp - zq)^2) into loss_out.
__global__ __launch_bounds__(256) void vq_scatter_loss(
        const float* __restrict__ z, const float* __restrict__ cb,
        const int* __restrict__ idx, float* __restrict__ out,
        float* __restrict__ loss_out) {
    int o = blockIdx.x * 256 + threadIdx.x;
    int k = o & 255;
    int j = (o >> 8) & 31;
    int i = (o >> 13) & 31;
    int b = o >> 18;
    int n = b * 1024 + j * 32 + (k >> 3);
    int e = idx[n];
    float zq = cb[e * CDIM + (k & 7) * 32 + i];
    float zp = z[((b * 256 + k) * 32 + i) * 32 + j];
    out[o] = zq;
    float d = zp - zq;
    float s = d * d;
#pragma unroll
    for (int off = 32; off >= 1; off >>= 1) s += __shfl_down(s, off, 64);
    __shared__ float wsum[4];
    int lane = threadIdx.x & 63, wv = threadIdx.x >> 6;
    if (lane == 0) wsum[wv] = s;
    __syncthreads();
    if (threadIdx.x == 0)
        atomicAdd(loss_out, (wsum[0] + wsum[1] + wsum[2] + wsum[3]) *
                            (1.25f / (float)NELEM));
}

// ---------------------------------------------------------------------------
extern "C" void kernel_launch(void* const* d_in, const int* in_sizes, int n_in,
                              void* d_out, int out_size, void* d_ws, size_t ws_size,
                              hipStream_t stream) {
    const float* z  = (const float*)d_in[0];
    const float* cb = (const float*)d_in[1];
    float* out = (float*)d_out;

    char* ws = (char*)d_ws;
    unsigned long long* packed = (unsigned long long*)ws;  // 131072 B
    float* z2w = (float*)(ws + 131072);                    // 65536 B
    int*   idx = (int*)(ws + 196608);                      // 65536 B

    hipMemsetAsync(ws, 0xFF, 131072, stream);              // packed = +inf keys
    hipMemsetAsync(out + NELEM, 0, 4, stream);             // loss accumulator

    vq_z2<<<NROWS / 256, 256, 0, stream>>>(z, z2w);

    dim3 grid(KENT / TK, NROWS / TM);                      // 64 x 128
    vq_scores<<<grid, 256, 0, stream>>>(z, cb, z2w, packed);

    vq_finalize_idx<<<NROWS / 256, 256, 0, stream>>>(packed, idx, out + NELEM + 1);

    vq_scatter_loss<<<NELEM / 256, 256, 0, stream>>>(z, cb, idx, out, out + NELEM);
}

// Round 3
// 853.808 us; speedup vs baseline: 1.2776x; 1.2776x over previous
//
#include <hip/hip_runtime.h>
#include <stdint.h>

// Problem constants
#define NROWS 16384   // B*H*W = 16*32*32
#define KENT  8192    // codebook entries
#define CDIM  256     // embedding dim
#define NELEM 4194304 // B*H*W*C elements of z / z_q

#define MARGIN_S 2.5e-4f   // screening margin in s-units (worst-case err ~1e-4)

// ws layout (bytes), total ~29.5 MB:
//   [0,        8388608): zbf2  u16[4194304]  z bf16, k-major tile layout
//   [8388608, 12582912): cbbf2 u16[2097152]  codebook bf16, same layout
//   [12582912,29360128): smax16 u16[8388608] per-(row,16col-group) bf16-up max
//   [29360128,29425664): z2w  float[16384]   np-tree row norms
//   [29425664,29491200): idx  int[16384]
//
// Tile layout for zbf2/cbbf2: panel p = row>>7 (128 rows), within panel:
//   u16 index = ((p*32 + (c>>3))*128 + (row&127))*8 + (c&7)
// => GEMM stage s (k0=s*32) reads panel_base + s*8192..+8192 bytes contiguous,
//    and LDS ends up k-major: chunk (q, r) at (q*128+r)*16B.

typedef short v8s __attribute__((ext_vector_type(8)));
typedef float v4f __attribute__((ext_vector_type(4)));

__device__ inline unsigned short f2bf_rne(float f) {
    unsigned b = __float_as_uint(f);
    return (unsigned short)((b + 0x7FFFu + ((b >> 16) & 1u)) >> 16);
}
__device__ inline unsigned short bf16_up(float f) {  // round toward +inf
    unsigned b = __float_as_uint(f);
    unsigned short h = (unsigned short)(b >> 16);
    if (!(b >> 31) && (b & 0xFFFFu)) h++;
    return h;
}
__device__ inline float bf16_dec(unsigned short h) {
    return __uint_as_float(((unsigned)h) << 16);
}
__device__ inline void gload_lds16(const void* g, void* l) {
    __builtin_amdgcn_global_load_lds(
        (const __attribute__((address_space(1))) void*)g,
        (__attribute__((address_space(3))) void*)l, 16, 0, 0);
}

// ---------------------------------------------------------------------------
// Per-row: z2 via the VALIDATED np AVX512 pairwise tree (round-2 verbatim),
// fused with bf16 conversion + transposed tile-layout store of z.
// 128 threads = 128 rows per block; LDS bf16 tile [128][258] (pad => 2-way banks).
__global__ __launch_bounds__(128) void vq_prep_z(
        const float* __restrict__ z, float* __restrict__ z2w,
        unsigned short* __restrict__ zbf2) {
    __shared__ unsigned short tile[128 * 258];
    const int t = threadIdx.x;
    const int n0 = blockIdx.x * 128;
    const int b = n0 >> 10, hw0 = n0 & 1023;
    const float* base = z + b * 262144 + hw0 + t;

    float bs[2];
#pragma unroll
    for (int blk = 0; blk < 2; ++blk) {
        float C[16];
#pragma unroll
        for (int L = 0; L < 16; ++L) {
            float q[8];
#pragma unroll
            for (int j = 0; j < 8; ++j) {
                int c = blk * 128 + L + 16 * j;
                float a = base[c * 1024];
                tile[t * 258 + c] = f2bf_rne(a);
                float sq = a * a;
                asm volatile("" : "+v"(sq));   // no FMA contraction into adds
                q[j] = sq;
            }
            C[L] = ((q[0] + q[1]) + (q[2] + q[3])) + ((q[4] + q[5]) + (q[6] + q[7]));
        }
        float t8[8];
#pragma unroll
        for (int L = 0; L < 8; ++L) t8[L] = C[L] + C[L + 8];
        float t4[4];
#pragma unroll
        for (int L = 0; L < 4; ++L) t4[L] = t8[L] + t8[L + 4];
        float t2a = t4[0] + t4[2];
        float t2b = t4[1] + t4[3];
        bs[blk] = t2a + t2b;
    }
    z2w[n0 + t] = bs[0] + bs[1];
    __syncthreads();

    // store tile in k-major chunk layout: chunk = it*128 + t => q=it, r=t
    unsigned short* dst = zbf2 + blockIdx.x * 32768;
#pragma unroll
    for (int it = 0; it < 32; ++it) {
        uint4 v;
        v.x = *(const unsigned int*)&tile[t * 258 + it * 8 + 0];
        v.y = *(const unsigned int*)&tile[t * 258 + it * 8 + 2];
        v.z = *(const unsigned int*)&tile[t * 258 + it * 8 + 4];
        v.w = *(const unsigned int*)&tile[t * 258 + it * 8 + 6];
        *(uint4*)&dst[(it * 128 + t) * 8] = v;
    }
}

// ---------------------------------------------------------------------------
// Codebook fp32 -> bf16 in the same tile layout. 64 blocks x 256 threads.
__global__ __launch_bounds__(256) void vq_prep_cb(
        const float* __restrict__ cb, unsigned short* __restrict__ cbbf2) {
    const int t = threadIdx.x, p = blockIdx.x, n0 = p * 128;
    unsigned short* dst = cbbf2 + p * 32768;
#pragma unroll
    for (int it = 0; it < 16; ++it) {
        int chunk = it * 256 + t;
        int q = chunk >> 7, r = chunk & 127;
        const float* src = cb + (n0 + r) * 256 + q * 8;
        float4 a = *(const float4*)src;
        float4 c = *(const float4*)(src + 4);
        uint4 v;
        v.x = (unsigned)f2bf_rne(a.x) | ((unsigned)f2bf_rne(a.y) << 16);
        v.y = (unsigned)f2bf_rne(a.z) | ((unsigned)f2bf_rne(a.w) << 16);
        v.z = (unsigned)f2bf_rne(c.x) | ((unsigned)f2bf_rne(c.y) << 16);
        v.w = (unsigned)f2bf_rne(c.z) | ((unsigned)f2bf_rne(c.w) << 16);
        *(uint4*)&dst[chunk * 8] = v;
    }
}

// ---------------------------------------------------------------------------
// bf16 MFMA screening GEMM: s~ = zbf . cbbf^T, 128x128 tile, BK=32, m97-style
// global_load_lds staging. Epilogue: per-row max over each 16-col group ->
// smax16[row][512] as bf16 rounded up.
__global__ __launch_bounds__(256, 2) void vq_gemm(
        const unsigned short* __restrict__ zbf2,
        const unsigned short* __restrict__ cbbf2,
        unsigned short* __restrict__ smax16) {
    __shared__ short As[4096];        // 512 chunks * 16B = 8KB, k-major
    __shared__ short Bs[4096];
    __shared__ float red[128][8];

    const int tid = threadIdx.x;
    const int w = tid >> 6, l = tid & 63;
    const int q = l >> 4, cl = l & 15;
    const int mw = w & 1, nw = w >> 1;
    const int pm = blockIdx.y, pn = blockIdx.x;

    const char* Ab = (const char*)(zbf2 + pm * 32768);
    const char* Bb = (const char*)(cbbf2 + pn * 32768);
    char* AsB = (char*)As;
    char* BsB = (char*)Bs;

    v4f acc[4][4];
#pragma unroll
    for (int i = 0; i < 4; ++i)
#pragma unroll
        for (int j = 0; j < 4; ++j) acc[i][j] = (v4f)0.f;

    for (int s = 0; s < 8; ++s) {
        if (s) __syncthreads();
        // stage: 8KB A + 8KB B, 2 issues each (lds dst: wave base + lane*16)
        gload_lds16(Ab + s * 8192 +        tid * 16, AsB +        (w << 10));
        gload_lds16(Ab + s * 8192 + 4096 + tid * 16, AsB + 4096 + (w << 10));
        gload_lds16(Bb + s * 8192 +        tid * 16, BsB +        (w << 10));
        gload_lds16(Bb + s * 8192 + 4096 + tid * 16, BsB + 4096 + (w << 10));
        __syncthreads();

        v8s af[4], bf[4];
#pragma unroll
        for (int i = 0; i < 4; ++i)
            af[i] = *(const v8s*)&As[(q * 128 + mw * 64 + i * 16 + cl) * 8];
#pragma unroll
        for (int j = 0; j < 4; ++j)
            bf[j] = *(const v8s*)&Bs[(q * 128 + nw * 64 + j * 16 + cl) * 8];
#pragma unroll
        for (int i = 0; i < 4; ++i)
#pragma unroll
            for (int j = 0; j < 4; ++j)
                acc[i][j] = __builtin_amdgcn_mfma_f32_16x16x32_bf16(
                    af[i], bf[j], acc[i][j], 0, 0, 0);
    }

    // epilogue: per 16x16 frag, max over its 16 cols for each of 16 rows
#pragma unroll
    for (int i = 0; i < 4; ++i)
#pragma unroll
        for (int j = 0; j < 4; ++j) {
            v4f v = acc[i][j];
#pragma unroll
            for (int off = 1; off < 16; off <<= 1) {
                v.x = fmaxf(v.x, __shfl_xor(v.x, off));
                v.y = fmaxf(v.y, __shfl_xor(v.y, off));
                v.z = fmaxf(v.z, __shfl_xor(v.z, off));
                v.w = fmaxf(v.w, __shfl_xor(v.w, off));
            }
            if (cl == 0) {
                int r0 = mw * 64 + i * 16 + q * 4;
                int g = nw * 4 + j;
                red[r0 + 0][g] = v.x;
                red[r0 + 1][g] = v.y;
                red[r0 + 2][g] = v.z;
                red[r0 + 3][g] = v.w;
            }
        }
    __syncthreads();
#pragma unroll
    for (int it = 0; it < 4; ++it) {
        int e = it * 256 + tid;
        int r = e >> 3, g = e & 7;
        smax16[(pm * 128 + r) * 512 + pn * 8 + g] = bf16_up(red[r][g]);
    }
}

// ---------------------------------------------------------------------------
// Exact rescore: per row (1 wave), screen 512 group maxes, rescore candidate
// 16-col groups with the validated fp32 chain; lowest-index tie via packed u64.
__global__ __launch_bounds__(64) void vq_stage2(
        const float* __restrict__ z, const float* __restrict__ cb,
        const float* __restrict__ z2w, const unsigned short* __restrict__ smax16,
        int* __restrict__ idx, float* __restrict__ out_idx) {
    const int row = blockIdx.x;
    const int l = threadIdx.x;
    const uint4 pv = *(const uint4*)(smax16 + row * 512 + l * 8);
    float f[8];
    f[0] = bf16_dec((unsigned short)(pv.x & 0xFFFF));
    f[1] = bf16_dec((unsigned short)(pv.x >> 16));
    f[2] = bf16_dec((unsigned short)(pv.y & 0xFFFF));
    f[3] = bf16_dec((unsigned short)(pv.y >> 16));
    f[4] = bf16_dec((unsigned short)(pv.z & 0xFFFF));
    f[5] = bf16_dec((unsigned short)(pv.z >> 16));
    f[6] = bf16_dec((unsigned short)(pv.w & 0xFFFF));
    f[7] = bf16_dec((unsigned short)(pv.w >> 16));
    float gmax = f[0];
#pragma unroll
    for (int j = 1; j < 8; ++j) gmax = fmaxf(gmax, f[j]);
#pragma unroll
    for (int off = 1; off < 64; off <<= 1) gmax = fmaxf(gmax, __shfl_xor(gmax, off));
    const float th = gmax - MARGIN_S;

    const int b = row >> 10, hw = row & 1023;
    const float* zr = z + b * 262144 + hw;
    const float z2v = z2w[row];
    unsigned long long best = ~0ull;

#pragma unroll
    for (int j = 0; j < 8; ++j) {
        unsigned long long m = __ballot(f[j] >= th);
        while (m) {
            int src = __ffsll((unsigned long long)m) - 1;
            m &= m - 1;
            int g = src * 8 + j;
            int k = g * 16 + (l & 15);          // lanes 16..63 duplicate: harmless
            const float* e = cb + k * 256;
            float s = 0.f;
#pragma unroll 16
            for (int c = 0; c < 256; ++c) s = __builtin_fmaf(zr[c * 1024], e[c], s);
            float d = z2v - 2.0f * s;           // single rounding (2*s exact)
            unsigned long long key =
                ((unsigned long long)__float_as_uint(d) << 32) | (unsigned)k;
#pragma unroll
            for (int off = 1; off < 64; off <<= 1) {
                unsigned long long o = __shfl_xor(key, off);
                if (o < key) key = o;
            }
            if (key < best) best = key;
        }
    }
    if (l == 0) {
        int k = (int)(unsigned)(best & 0xFFFFFFFFu);
        idx[row] = k;
        out_idx[row] = (float)k;
    }
}

// ---------------------------------------------------------------------------
// z_q scatter in OUTPUT order (coalesced store) + fused loss accumulation.
__global__ __launch_bounds__(256) void vq_scatter_loss(
        const float* __restrict__ z, const float* __restrict__ cb,
        const int* __restrict__ idx, float* __restrict__ out,
        float* __restrict__ loss_out) {
    int o = blockIdx.x * 256 + threadIdx.x;
    int k = o & 255;
    int j = (o >> 8) & 31;
    int i = (o >> 13) & 31;
    int b = o >> 18;
    int n = b * 1024 + j * 32 + (k >> 3);
    int e = idx[n];
    float zq = cb[e * CDIM + (k & 7) * 32 + i];
    float zp = z[((b * 256 + k) * 32 + i) * 32 + j];
    out[o] = zq;
    float d = zp - zq;
    float s = d * d;
#pragma unroll
    for (int off = 32; off >= 1; off >>= 1) s += __shfl_down(s, off, 64);
    __shared__ float wsum[4];
    int lane = threadIdx.x & 63, wv = threadIdx.x >> 6;
    if (lane == 0) wsum[wv] = s;
    __syncthreads();
    if (threadIdx.x == 0)
        atomicAdd(loss_out, (wsum[0] + wsum[1] + wsum[2] + wsum[3]) *
                            (1.25f / (float)NELEM));
}

// ---------------------------------------------------------------------------
extern "C" void kernel_launch(void* const* d_in, const int* in_sizes, int n_in,
                              void* d_out, int out_size, void* d_ws, size_t ws_size,
                              hipStream_t stream) {
    const float* z  = (const float*)d_in[0];
    const float* cb = (const float*)d_in[1];
    float* out = (float*)d_out;

    char* ws = (char*)d_ws;
    unsigned short* zbf2   = (unsigned short*)ws;
    unsigned short* cbbf2  = (unsigned short*)(ws + 8388608);
    unsigned short* smax16 = (unsigned short*)(ws + 12582912);
    float* z2w             = (float*)(ws + 29360128);
    int*   idx             = (int*)(ws + 29425664);

    hipMemsetAsync(out + NELEM, 0, 4, stream);   // loss accumulator

    vq_prep_z<<<NROWS / 128, 128, 0, stream>>>(z, z2w, zbf2);
    vq_prep_cb<<<KENT / 128, 256, 0, stream>>>(cb, cbbf2);

    dim3 ggrid(KENT / 128, NROWS / 128);         // 64 x 128
    vq_gemm<<<ggrid, 256, 0, stream>>>(zbf2, cbbf2, smax16);

    vq_stage2<<<NROWS, 64, 0, stream>>>(z, cb, z2w, smax16, idx, out + NELEM + 1);

    vq_scatter_loss<<<NELEM / 256, 256, 0, stream>>>(z, cb, idx, out, out + NELEM);
}

// Round 4
// 603.757 us; speedup vs baseline: 1.8068x; 1.4142x over previous
//
#include <hip/hip_runtime.h>
#include <stdint.h>

// Problem constants
#define NROWS 16384   // B*H*W = 16*32*32
#define KENT  8192    // codebook entries
#define CDIM  256     // embedding dim
#define NELEM 4194304 // B*H*W*C elements of z / z_q

#define MARGIN 1.5e-4f   // >=30 sigma of bf16-screen error (rms ~3e-6)

// ws layout (bytes), total 29,750,400 (~28.4 MiB):
//   [0,        8388608): zbf2  u16[4M]   z bf16, k-major tile layout
//   [8388608, 12582912): cbbf2 u16[2M]   codebook bf16, same layout
//   [12582912,29360128): cand  u64[16384][128]  (score_bits<<32 | k)
//   [29360128,29425664): z2w   float[16384]
//   [29425664,29491200): idx   int[16384]
//   [29491200,29556736): gmax  u32[16384]  monotone-mapped row max   -- memset 0
//   [29556736,29622272): cnt   u32[16384]  candidate counts          -- memset 0
//   [29622272,29750400): bestkey u64[16384]                          -- memset FF

typedef short v8s __attribute__((ext_vector_type(8)));
typedef float v4f __attribute__((ext_vector_type(4)));

__device__ inline unsigned short f2bf_rne(float f) {
    unsigned b = __float_as_uint(f);
    return (unsigned short)((b + 0x7FFFu + ((b >> 16) & 1u)) >> 16);
}
__device__ inline unsigned mono(float f) {   // order-preserving float->u32
    unsigned b = __float_as_uint(f);
    return (b & 0x80000000u) ? ~b : (b | 0x80000000u);
}
__device__ inline float dmono(unsigned u) {
    unsigned b = (u & 0x80000000u) ? (u ^ 0x80000000u) : ~u;
    return __uint_as_float(b);
}
__device__ inline void gload_lds16(const void* g, void* l) {
    __builtin_amdgcn_global_load_lds(
        (const __attribute__((address_space(1))) void*)g,
        (__attribute__((address_space(3))) void*)l, 16, 0, 0);
}

// ---------------------------------------------------------------------------
// Per-row z2 via the VALIDATED np AVX512 pairwise tree + bf16 tile-layout copy.
__global__ __launch_bounds__(128) void vq_prep_z(
        const float* __restrict__ z, float* __restrict__ z2w,
        unsigned short* __restrict__ zbf2) {
    __shared__ unsigned short tile[128 * 258];
    const int t = threadIdx.x;
    const int n0 = blockIdx.x * 128;
    const int b = n0 >> 10, hw0 = n0 & 1023;
    const float* base = z + b * 262144 + hw0 + t;

    float bs[2];
#pragma unroll
    for (int blk = 0; blk < 2; ++blk) {
        float C[16];
#pragma unroll
        for (int L = 0; L < 16; ++L) {
            float q[8];
#pragma unroll
            for (int j = 0; j < 8; ++j) {
                int c = blk * 128 + L + 16 * j;
                float a = base[c * 1024];
                tile[t * 258 + c] = f2bf_rne(a);
                float sq = a * a;
                asm volatile("" : "+v"(sq));   // no FMA contraction into adds
                q[j] = sq;
            }
            C[L] = ((q[0] + q[1]) + (q[2] + q[3])) + ((q[4] + q[5]) + (q[6] + q[7]));
        }
        float t8[8];
#pragma unroll
        for (int L = 0; L < 8; ++L) t8[L] = C[L] + C[L + 8];
        float t4[4];
#pragma unroll
        for (int L = 0; L < 4; ++L) t4[L] = t8[L] + t8[L + 4];
        float t2a = t4[0] + t4[2];
        float t2b = t4[1] + t4[3];
        bs[blk] = t2a + t2b;
    }
    z2w[n0 + t] = bs[0] + bs[1];
    __syncthreads();

    unsigned short* dst = zbf2 + blockIdx.x * 32768;
#pragma unroll
    for (int it = 0; it < 32; ++it) {
        uint4 v;
        v.x = *(const unsigned int*)&tile[t * 258 + it * 8 + 0];
        v.y = *(const unsigned int*)&tile[t * 258 + it * 8 + 2];
        v.z = *(const unsigned int*)&tile[t * 258 + it * 8 + 4];
        v.w = *(const unsigned int*)&tile[t * 258 + it * 8 + 6];
        *(uint4*)&dst[(it * 128 + t) * 8] = v;
    }
}

// ---------------------------------------------------------------------------
__global__ __launch_bounds__(256) void vq_prep_cb(
        const float* __restrict__ cb, unsigned short* __restrict__ cbbf2) {
    const int t = threadIdx.x, p = blockIdx.x, n0 = p * 128;
    unsigned short* dst = cbbf2 + p * 32768;
#pragma unroll
    for (int it = 0; it < 16; ++it) {
        int chunk = it * 256 + t;
        int q = chunk >> 7, r = chunk & 127;
        const float* src = cb + (n0 + r) * 256 + q * 8;
        float4 a = *(const float4*)src;
        float4 c = *(const float4*)(src + 4);
        uint4 v;
        v.x = (unsigned)f2bf_rne(a.x) | ((unsigned)f2bf_rne(a.y) << 16);
        v.y = (unsigned)f2bf_rne(a.z) | ((unsigned)f2bf_rne(a.w) << 16);
        v.z = (unsigned)f2bf_rne(c.x) | ((unsigned)f2bf_rne(c.y) << 16);
        v.w = (unsigned)f2bf_rne(c.z) | ((unsigned)f2bf_rne(c.w) << 16);
        *(uint4*)&dst[chunk * 8] = v;
    }
}

// ---------------------------------------------------------------------------
// bf16 MFMA screen. Epilogue: per-row block-local max -> global atomicMax,
// push all scores >= blockmax - MARGIN (superset of the final candidate set).
__global__ __launch_bounds__(256, 2) void vq_gemm(
        const unsigned short* __restrict__ zbf2,
        const unsigned short* __restrict__ cbbf2,
        unsigned* __restrict__ gmax, unsigned* __restrict__ cnt,
        unsigned long long* __restrict__ cand) {
    __shared__ short As[4096];        // 8KB, k-major chunks
    __shared__ short Bs[4096];
    __shared__ float red2[128][2];
    __shared__ float thL[128];

    const int tid = threadIdx.x;
    const int w = tid >> 6, l = tid & 63;
    const int q = l >> 4, cl = l & 15;
    const int mw = w & 1, nw = w >> 1;
    const int pm = blockIdx.y, pn = blockIdx.x;
    const int n0 = pm * 128;

    const char* Ab = (const char*)(zbf2 + pm * 32768);
    const char* Bb = (const char*)(cbbf2 + pn * 32768);
    char* AsB = (char*)As;
    char* BsB = (char*)Bs;

    v4f acc[4][4];
#pragma unroll
    for (int i = 0; i < 4; ++i)
#pragma unroll
        for (int j = 0; j < 4; ++j) acc[i][j] = (v4f)0.f;

    for (int s = 0; s < 8; ++s) {
        if (s) __syncthreads();
        gload_lds16(Ab + s * 8192 +        tid * 16, AsB +        (w << 10));
        gload_lds16(Ab + s * 8192 + 4096 + tid * 16, AsB + 4096 + (w << 10));
        gload_lds16(Bb + s * 8192 +        tid * 16, BsB +        (w << 10));
        gload_lds16(Bb + s * 8192 + 4096 + tid * 16, BsB + 4096 + (w << 10));
        __syncthreads();

        v8s af[4], bf[4];
#pragma unroll
        for (int i = 0; i < 4; ++i)
            af[i] = *(const v8s*)&As[(q * 128 + mw * 64 + i * 16 + cl) * 8];
#pragma unroll
        for (int j = 0; j < 4; ++j)
            bf[j] = *(const v8s*)&Bs[(q * 128 + nw * 64 + j * 16 + cl) * 8];
#pragma unroll
        for (int i = 0; i < 4; ++i)
#pragma unroll
            for (int j = 0; j < 4; ++j)
                acc[i][j] = __builtin_amdgcn_mfma_f32_16x16x32_bf16(
                    af[i], bf[j], acc[i][j], 0, 0, 0);
    }

    // per-lane row maxes over this wave's 64 cols
    float pmx[4][4];
#pragma unroll
    for (int i = 0; i < 4; ++i) {
        v4f m = acc[i][0];
#pragma unroll
        for (int j = 1; j < 4; ++j) {
            m.x = fmaxf(m.x, acc[i][j].x); m.y = fmaxf(m.y, acc[i][j].y);
            m.z = fmaxf(m.z, acc[i][j].z); m.w = fmaxf(m.w, acc[i][j].w);
        }
        pmx[i][0] = m.x; pmx[i][1] = m.y; pmx[i][2] = m.z; pmx[i][3] = m.w;
#pragma unroll
        for (int g = 0; g < 4; ++g)
#pragma unroll
            for (int off = 1; off < 16; off <<= 1)
                pmx[i][g] = fmaxf(pmx[i][g], __shfl_xor(pmx[i][g], off));
    }
    if (cl == 0) {
#pragma unroll
        for (int i = 0; i < 4; ++i)
#pragma unroll
            for (int g = 0; g < 4; ++g)
                red2[mw * 64 + i * 16 + q * 4 + g][nw] = pmx[i][g];
    }
    __syncthreads();
    if (tid < 128) {
        float bm = fmaxf(red2[tid][0], red2[tid][1]);
        atomicMax(&gmax[n0 + tid], mono(bm));
        thL[tid] = bm - MARGIN;
    }
    __syncthreads();

    // push candidates (vs block-local threshold => superset of final set)
#pragma unroll
    for (int i = 0; i < 4; ++i)
#pragma unroll
        for (int g = 0; g < 4; ++g) {
            int r = mw * 64 + i * 16 + q * 4 + g;
            float th = thL[r];
#pragma unroll
            for (int j = 0; j < 4; ++j) {
                float s = acc[i][j][g];
                if (s >= th) {
                    unsigned slot = atomicAdd(&cnt[n0 + r], 1u);
                    if (slot < 128u) {
                        unsigned k = pn * 128 + nw * 64 + j * 16 + cl;
                        cand[(unsigned)(n0 + r) * 128u + slot] =
                            ((unsigned long long)__float_as_uint(s) << 32) | k;
                    }
                }
            }
        }
}

// ---------------------------------------------------------------------------
// Exact rescore: block = 128 rows. Filter pushed candidates by the global max,
// then one exact serial-FMA chain per candidate per thread, z staged via LDS.
__global__ __launch_bounds__(256) void vq_rescore(
        const float* __restrict__ z, const float* __restrict__ cb,
        const float* __restrict__ z2w, const unsigned* __restrict__ gmax,
        const unsigned* __restrict__ cnt, const unsigned long long* __restrict__ cand,
        unsigned long long* __restrict__ bestkey) {
    __shared__ float zs[32][128];
    __shared__ float thrL[128];
    __shared__ unsigned short cntc[128];
    __shared__ unsigned candL[512];    // (r<<13)|k
    __shared__ unsigned blkcnt;

    const int t = threadIdx.x;
    const int n0 = blockIdx.x * 128;
    const int b = n0 >> 10, hw0 = n0 & 1023;

    if (t < 128) {
        unsigned c = cnt[n0 + t];
        cntc[t] = (unsigned short)(c < 128u ? c : 128u);
        thrL[t] = dmono(gmax[n0 + t]) - MARGIN;
    }
    if (t == 0) blkcnt = 0;
    __syncthreads();

    {   // filter: 2 threads per row scan its slots
        int r = t >> 1;
        int c = cntc[r];
        for (int s = (t & 1); s < c; s += 2) {
            unsigned long long e = cand[(unsigned)(n0 + r) * 128u + s];
            float sf = __uint_as_float((unsigned)(e >> 32));
            if (sf >= thrL[r]) {
                unsigned pos = atomicAdd(&blkcnt, 1u);
                if (pos < 512u)
                    candL[pos] = ((unsigned)r << 13) | (unsigned)(e & 0x1FFFu);
            }
        }
    }
    __syncthreads();
    int ns = (int)(blkcnt < 512u ? blkcnt : 512u);

    for (int base = 0; base < ns; base += 256) {
        bool active = base + t < ns;
        int r = 0, k = 0;
        if (active) {
            unsigned v = candL[base + t];
            r = v >> 13; k = v & 8191;
        }
        float sacc = 0.f;
        for (int ch = 0; ch < 8; ++ch) {
            __syncthreads();
            {   // stage 32 channels x 128 rows, coalesced
                int rr = t & 127, cc2 = t >> 7;
#pragma unroll
                for (int u = 0; u < 16; ++u) {
                    int cc = u * 2 + cc2;
                    zs[cc][rr] = z[b * 262144 + (ch * 32 + cc) * 1024 + hw0 + rr];
                }
            }
            __syncthreads();
            if (active) {
                const float4* cbp = (const float4*)(cb + k * 256 + ch * 32);
                float4 A0 = cbp[0], A1 = cbp[1], A2 = cbp[2], A3 = cbp[3];
                float4 A4 = cbp[4], A5 = cbp[5], A6 = cbp[6], A7 = cbp[7];
                float Af[32] = {A0.x,A0.y,A0.z,A0.w, A1.x,A1.y,A1.z,A1.w,
                                A2.x,A2.y,A2.z,A2.w, A3.x,A3.y,A3.z,A3.w,
                                A4.x,A4.y,A4.z,A4.w, A5.x,A5.y,A5.z,A5.w,
                                A6.x,A6.y,A6.z,A6.w, A7.x,A7.y,A7.z,A7.w};
#pragma unroll
                for (int u = 0; u < 32; ++u)
                    sacc = __builtin_fmaf(zs[u][r], Af[u], sacc);
            }
        }
        if (active) {
            float d = z2w[n0 + r] - 2.0f * sacc;   // single rounding, d > 0
            unsigned long long key =
                ((unsigned long long)__float_as_uint(d) << 32) | (unsigned)k;
            atomicMin(&bestkey[n0 + r], key);
        }
    }
}

// ---------------------------------------------------------------------------
__global__ void vq_finalize_idx(const unsigned long long* __restrict__ bestkey,
                                int* __restrict__ idx, float* __restrict__ out_idx) {
    int n = blockIdx.x * 256 + threadIdx.x;
    int k = (int)(unsigned)(bestkey[n] & 0xFFFFFFFFu);
    idx[n] = k;
    out_idx[n] = (float)k;
}

// ---------------------------------------------------------------------------
// Scatter + loss, block = (b, i). z staged via LDS transpose (coalesced reads),
// out writes coalesced. out[b,i,j,k] = cb[idx[b*1024+j*32+(k>>3)]][(k&7)*32+i].
__global__ __launch_bounds__(256) void vq_scatter_loss(
        const float* __restrict__ z, const float* __restrict__ cb,
        const int* __restrict__ idx, float* __restrict__ out,
        float* __restrict__ loss_out) {
    __shared__ float zs2[256][33];
    __shared__ int idxs[1024];
    __shared__ float wsum[4];

    const int t = threadIdx.x;
    const int b = blockIdx.x >> 5, i = blockIdx.x & 31;

#pragma unroll
    for (int it = 0; it < 32; ++it) {
        int k = it * 8 + (t >> 5);
        zs2[k][t & 31] = z[b * 262144 + k * 1024 + i * 32 + (t & 31)];
    }
#pragma unroll
    for (int u = 0; u < 4; ++u)
        idxs[u * 256 + t] = idx[b * 1024 + u * 256 + t];
    __syncthreads();

    float lsum = 0.f;
    float* obase = out + b * 262144 + i * 8192;
#pragma unroll 4
    for (int j = 0; j < 32; ++j) {
        int e = idxs[j * 32 + (t >> 3)];
        float zq = cb[e * 256 + (t & 7) * 32 + i];
        float zp = zs2[t][j];
        obase[j * 256 + t] = zq;
        float d = zp - zq;
        lsum = __builtin_fmaf(d, d, lsum);
    }
#pragma unroll
    for (int off = 32; off >= 1; off >>= 1) lsum += __shfl_down(lsum, off, 64);
    int lane = t & 63, wv = t >> 6;
    if (lane == 0) wsum[wv] = lsum;
    __syncthreads();
    if (t == 0)
        atomicAdd(loss_out, (wsum[0] + wsum[1] + wsum[2] + wsum[3]) *
                            (1.25f / (float)NELEM));
}

// ---------------------------------------------------------------------------
extern "C" void kernel_launch(void* const* d_in, const int* in_sizes, int n_in,
                              void* d_out, int out_size, void* d_ws, size_t ws_size,
                              hipStream_t stream) {
    const float* z  = (const float*)d_in[0];
    const float* cb = (const float*)d_in[1];
    float* out = (float*)d_out;

    char* ws = (char*)d_ws;
    unsigned short* zbf2   = (unsigned short*)ws;
    unsigned short* cbbf2  = (unsigned short*)(ws + 8388608);
    unsigned long long* cand = (unsigned long long*)(ws + 12582912);
    float* z2w             = (float*)(ws + 29360128);
    int*   idx             = (int*)(ws + 29425664);
    unsigned* gmax         = (unsigned*)(ws + 29491200);
    unsigned* cnt          = (unsigned*)(ws + 29556736);
    unsigned long long* bestkey = (unsigned long long*)(ws + 29622272);

    hipMemsetAsync(ws + 29491200, 0, 131072, stream);     // gmax + cnt
    hipMemsetAsync(ws + 29622272, 0xFF, 131072, stream);  // bestkey
    hipMemsetAsync(out + NELEM, 0, 4, stream);            // loss accumulator

    vq_prep_z<<<NROWS / 128, 128, 0, stream>>>(z, z2w, zbf2);
    vq_prep_cb<<<KENT / 128, 256, 0, stream>>>(cb, cbbf2);

    dim3 ggrid(KENT / 128, NROWS / 128);                  // 64 x 128
    vq_gemm<<<ggrid, 256, 0, stream>>>(zbf2, cbbf2, gmax, cnt, cand);

    vq_rescore<<<NROWS / 128, 256, 0, stream>>>(z, cb, z2w, gmax, cnt, cand, bestkey);

    vq_finalize_idx<<<NROWS / 256, 256, 0, stream>>>(bestkey, idx, out + NELEM + 1);

    vq_scatter_loss<<<512, 256, 0, stream>>>(z, cb, idx, out, out + NELEM);
}

// Round 5
// 327.742 us; speedup vs baseline: 3.3284x; 1.8422x over previous
//
#include <hip/hip_runtime.h>
#include <stdint.h>

// Problem constants
#define NROWS 16384   // B*H*W = 16*32*32
#define KENT  8192    // codebook entries
#define CDIM  256     // embedding dim
#define NELEM 4194304 // B*H*W*C elements of z / z_q

#define MARGIN 1.5e-4f   // >=30 sigma of bf16-screen error (rms ~3e-6)

// ws layout (bytes), total 29,750,400 (~28.4 MiB):
//   [0,        8388608): zbf2  u16[4M]   z bf16, k-major tile layout
//   [8388608, 12582912): cbbf2 u16[2M]   codebook bf16, same layout
//   [12582912,29360128): cand  u64[16384][128]  (score_bits<<32 | k)
//   [29360128,29425664): z2w   float[16384]
//   [29425664,29491200): idx   int[16384]
//   [29491200,29556736): gmax  u32[16384]  monotone-mapped row max   -- memset 0
//   [29556736,29622272): cnt   u32[16384]  candidate counts          -- memset 0
//   [29622272,29750400): bestkey u64[16384]                          -- memset FF

typedef short v8s __attribute__((ext_vector_type(8)));
typedef float v4f __attribute__((ext_vector_type(4)));

__device__ inline unsigned short f2bf_rne(float f) {
    unsigned b = __float_as_uint(f);
    return (unsigned short)((b + 0x7FFFu + ((b >> 16) & 1u)) >> 16);
}
__device__ inline unsigned mono(float f) {   // order-preserving float->u32
    unsigned b = __float_as_uint(f);
    return (b & 0x80000000u) ? ~b : (b | 0x80000000u);
}
__device__ inline float dmono(unsigned u) {
    unsigned b = (u & 0x80000000u) ? (u ^ 0x80000000u) : ~u;
    return __uint_as_float(b);
}
__device__ inline void gload_lds16(const void* g, void* l) {
    __builtin_amdgcn_global_load_lds(
        (const __attribute__((address_space(1))) void*)g,
        (__attribute__((address_space(3))) void*)l, 16, 0, 0);
}

// ---------------------------------------------------------------------------
// Per-row z2 via the VALIDATED np AVX512 pairwise tree + bf16 tile-layout copy.
__global__ __launch_bounds__(128) void vq_prep_z(
        const float* __restrict__ z, float* __restrict__ z2w,
        unsigned short* __restrict__ zbf2) {
    __shared__ unsigned short tile[128 * 258];
    const int t = threadIdx.x;
    const int n0 = blockIdx.x * 128;
    const int b = n0 >> 10, hw0 = n0 & 1023;
    const float* base = z + b * 262144 + hw0 + t;

    float bs[2];
#pragma unroll
    for (int blk = 0; blk < 2; ++blk) {
        float C[16];
#pragma unroll
        for (int L = 0; L < 16; ++L) {
            float q[8];
#pragma unroll
            for (int j = 0; j < 8; ++j) {
                int c = blk * 128 + L + 16 * j;
                float a = base[c * 1024];
                tile[t * 258 + c] = f2bf_rne(a);
                float sq = a * a;
                asm volatile("" : "+v"(sq));   // no FMA contraction into adds
                q[j] = sq;
            }
            C[L] = ((q[0] + q[1]) + (q[2] + q[3])) + ((q[4] + q[5]) + (q[6] + q[7]));
        }
        float t8[8];
#pragma unroll
        for (int L = 0; L < 8; ++L) t8[L] = C[L] + C[L + 8];
        float t4[4];
#pragma unroll
        for (int L = 0; L < 4; ++L) t4[L] = t8[L] + t8[L + 4];
        float t2a = t4[0] + t4[2];
        float t2b = t4[1] + t4[3];
        bs[blk] = t2a + t2b;
    }
    z2w[n0 + t] = bs[0] + bs[1];
    __syncthreads();

    unsigned short* dst = zbf2 + blockIdx.x * 32768;
#pragma unroll
    for (int it = 0; it < 32; ++it) {
        uint4 v;
        v.x = *(const unsigned int*)&tile[t * 258 + it * 8 + 0];
        v.y = *(const unsigned int*)&tile[t * 258 + it * 8 + 2];
        v.z = *(const unsigned int*)&tile[t * 258 + it * 8 + 4];
        v.w = *(const unsigned int*)&tile[t * 258 + it * 8 + 6];
        *(uint4*)&dst[(it * 128 + t) * 8] = v;
    }
}

// ---------------------------------------------------------------------------
__global__ __launch_bounds__(256) void vq_prep_cb(
        const float* __restrict__ cb, unsigned short* __restrict__ cbbf2) {
    const int t = threadIdx.x, p = blockIdx.x, n0 = p * 128;
    unsigned short* dst = cbbf2 + p * 32768;
#pragma unroll
    for (int it = 0; it < 16; ++it) {
        int chunk = it * 256 + t;
        int q = chunk >> 7, r = chunk & 127;
        const float* src = cb + (n0 + r) * 256 + q * 8;
        float4 a = *(const float4*)src;
        float4 c = *(const float4*)(src + 4);
        uint4 v;
        v.x = (unsigned)f2bf_rne(a.x) | ((unsigned)f2bf_rne(a.y) << 16);
        v.y = (unsigned)f2bf_rne(a.z) | ((unsigned)f2bf_rne(a.w) << 16);
        v.z = (unsigned)f2bf_rne(c.x) | ((unsigned)f2bf_rne(c.y) << 16);
        v.w = (unsigned)f2bf_rne(c.z) | ((unsigned)f2bf_rne(c.w) << 16);
        *(uint4*)&dst[chunk * 8] = v;
    }
}

// ---------------------------------------------------------------------------
// bf16 MFMA screen, v2:
//  - XCD-locality swizzle: each XCD owns 16 pm-panels and phases through
//    groups of 16 pn-panels => ~2MB working set per XCD L2 (vs 12MB thrash).
//  - BK=64: 4 stages, 16 MFMA per barrier.
//  - Epilogue: LDS-compacted candidate push, ONE global atomicAdd per row.
#define AS_OFF 0
#define BS_OFF 16384
#define RED2_OFF 32768
#define THL_OFF 33792
#define LCNT_OFF 34304
#define BASES_OFF 34816
#define SMEM_SZ 35328

__global__ __launch_bounds__(256, 4) void vq_gemm(
        const unsigned short* __restrict__ zbf2,
        const unsigned short* __restrict__ cbbf2,
        unsigned* __restrict__ gmax, unsigned* __restrict__ cnt,
        unsigned long long* __restrict__ cand) {
    __shared__ __align__(16) char smem[SMEM_SZ];
    short* As = (short*)(smem + AS_OFF);
    short* Bs = (short*)(smem + BS_OFF);
    float (*red2)[2] = (float(*)[2])(smem + RED2_OFF);
    float* thL = (float*)(smem + THL_OFF);
    unsigned* lcnt = (unsigned*)(smem + LCNT_OFF);
    unsigned* bases = (unsigned*)(smem + BASES_OFF);
    unsigned long long* lcand = (unsigned long long*)smem;  // aliases As post-loop

    const int tid = threadIdx.x;
    const int w = tid >> 6, l = tid & 63;
    const int q4 = l >> 4, cl = l & 15;
    const int mw = w & 1, nw = w >> 1;

    // swizzle: xcd-local phases of 16 pn over 16 pm
    const unsigned bx = blockIdx.x;
    const unsigned xcd = bx & 7, local = bx >> 3;
    const unsigned png = local >> 8;          // 0..3
    const unsigned rem = local & 255;
    const unsigned pm = (rem >> 4) * 8 + xcd; // 0..127
    const unsigned pn = png * 16 + (rem & 15);
    const int n0 = pm * 128;

    const char* Ab = (const char*)(zbf2 + pm * 32768);
    const char* Bb = (const char*)(cbbf2 + pn * 32768);

    v4f acc[4][4];
#pragma unroll
    for (int i = 0; i < 4; ++i)
#pragma unroll
        for (int j = 0; j < 4; ++j) acc[i][j] = (v4f)0.f;

    for (int s = 0; s < 4; ++s) {
        if (s) __syncthreads();
#pragma unroll
        for (int u = 0; u < 4; ++u) {
            gload_lds16(Ab + s * 16384 + u * 4096 + tid * 16,
                        (char*)As + u * 4096 + (w << 10));
            gload_lds16(Bb + s * 16384 + u * 4096 + tid * 16,
                        (char*)Bs + u * 4096 + (w << 10));
        }
        __syncthreads();
#pragma unroll
        for (int t = 0; t < 2; ++t) {
            v8s af[4], bf[4];
#pragma unroll
            for (int i = 0; i < 4; ++i)
                af[i] = *(const v8s*)&As[((t * 4 + q4) * 128 + mw * 64 + i * 16 + cl) * 8];
#pragma unroll
            for (int j = 0; j < 4; ++j)
                bf[j] = *(const v8s*)&Bs[((t * 4 + q4) * 128 + nw * 64 + j * 16 + cl) * 8];
#pragma unroll
            for (int i = 0; i < 4; ++i)
#pragma unroll
                for (int j = 0; j < 4; ++j)
                    acc[i][j] = __builtin_amdgcn_mfma_f32_16x16x32_bf16(
                        af[i], bf[j], acc[i][j], 0, 0, 0);
        }
    }

    // per-lane row maxes over this wave's 64 cols
    float pmx[4][4];
#pragma unroll
    for (int i = 0; i < 4; ++i) {
        v4f m = acc[i][0];
#pragma unroll
        for (int j = 1; j < 4; ++j) {
            m.x = fmaxf(m.x, acc[i][j].x); m.y = fmaxf(m.y, acc[i][j].y);
            m.z = fmaxf(m.z, acc[i][j].z); m.w = fmaxf(m.w, acc[i][j].w);
        }
        pmx[i][0] = m.x; pmx[i][1] = m.y; pmx[i][2] = m.z; pmx[i][3] = m.w;
#pragma unroll
        for (int g = 0; g < 4; ++g)
#pragma unroll
            for (int off = 1; off < 16; off <<= 1)
                pmx[i][g] = fmaxf(pmx[i][g], __shfl_xor(pmx[i][g], off));
    }
    __syncthreads();   // frags fully consumed; LDS reusable after next barrier
    if (cl == 0) {
#pragma unroll
        for (int i = 0; i < 4; ++i)
#pragma unroll
            for (int g = 0; g < 4; ++g)
                red2[mw * 64 + i * 16 + q4 * 4 + g][nw] = pmx[i][g];
    }
    __syncthreads();
    if (tid < 128) {
        float bm = fmaxf(red2[tid][0], red2[tid][1]);
        atomicMax(&gmax[n0 + tid], mono(bm));
        thL[tid] = bm - MARGIN;
        lcnt[tid] = 0;
    }
    __syncthreads();

    // compact candidate push into LDS (fast ds atomics)
#pragma unroll
    for (int i = 0; i < 4; ++i)
#pragma unroll
        for (int g = 0; g < 4; ++g) {
            int r = mw * 64 + i * 16 + q4 * 4 + g;
            float th = thL[r];
#pragma unroll
            for (int j = 0; j < 4; ++j) {
                float s = acc[i][j][g];
                if (s >= th) {
                    unsigned slot = atomicAdd(&lcnt[r], 1u);
                    if (slot < 8u) {
                        unsigned k = pn * 128 + nw * 64 + j * 16 + cl;
                        lcand[r * 8 + slot] =
                            ((unsigned long long)__float_as_uint(s) << 32) | k;
                    }
                }
            }
        }
    __syncthreads();
    if (tid < 128) {
        unsigned m = lcnt[tid] < 8u ? lcnt[tid] : 8u;
        bases[tid] = atomicAdd(&cnt[n0 + tid], m);   // one lane-parallel atomic
    }
    __syncthreads();
#pragma unroll
    for (int e0 = 0; e0 < 1024; e0 += 256) {
        int e = e0 + tid;
        int r = e >> 3, s2 = e & 7;
        unsigned m = lcnt[r] < 8u ? lcnt[r] : 8u;
        if ((unsigned)s2 < m) {
            unsigned pos = bases[r] + (unsigned)s2;
            if (pos < 128u)
                cand[(unsigned)(n0 + r) * 128u + pos] = lcand[e];
        }
    }
}

// ---------------------------------------------------------------------------
// Exact rescore: block = 128 rows. Filter pushed candidates by the global max,
// then one exact serial-FMA chain per candidate per thread, z staged via LDS.
__global__ __launch_bounds__(256) void vq_rescore(
        const float* __restrict__ z, const float* __restrict__ cb,
        const float* __restrict__ z2w, const unsigned* __restrict__ gmax,
        const unsigned* __restrict__ cnt, const unsigned long long* __restrict__ cand,
        unsigned long long* __restrict__ bestkey) {
    __shared__ float zs[32][128];
    __shared__ float thrL[128];
    __shared__ unsigned short cntc[128];
    __shared__ unsigned candL[512];    // (r<<13)|k
    __shared__ unsigned blkcnt;

    const int t = threadIdx.x;
    const int n0 = blockIdx.x * 128;
    const int b = n0 >> 10, hw0 = n0 & 1023;

    if (t < 128) {
        unsigned c = cnt[n0 + t];
        cntc[t] = (unsigned short)(c < 128u ? c : 128u);
        thrL[t] = dmono(gmax[n0 + t]) - MARGIN;
    }
    if (t == 0) blkcnt = 0;
    __syncthreads();

    {   // filter: 2 threads per row scan its slots
        int r = t >> 1;
        int c = cntc[r];
        for (int s = (t & 1); s < c; s += 2) {
            unsigned long long e = cand[(unsigned)(n0 + r) * 128u + s];
            float sf = __uint_as_float((unsigned)(e >> 32));
            if (sf >= thrL[r]) {
                unsigned pos = atomicAdd(&blkcnt, 1u);
                if (pos < 512u)
                    candL[pos] = ((unsigned)r << 13) | (unsigned)(e & 0x1FFFu);
            }
        }
    }
    __syncthreads();
    int ns = (int)(blkcnt < 512u ? blkcnt : 512u);

    for (int base = 0; base < ns; base += 256) {
        bool active = base + t < ns;
        int r = 0, k = 0;
        if (active) {
            unsigned v = candL[base + t];
            r = v >> 13; k = v & 8191;
        }
        float sacc = 0.f;
        for (int ch = 0; ch < 8; ++ch) {
            __syncthreads();
            {   // stage 32 channels x 128 rows, coalesced
                int rr = t & 127, cc2 = t >> 7;
#pragma unroll
                for (int u = 0; u < 16; ++u) {
                    int cc = u * 2 + cc2;
                    zs[cc][rr] = z[b * 262144 + (ch * 32 + cc) * 1024 + hw0 + rr];
                }
            }
            __syncthreads();
            if (active) {
                const float4* cbp = (const float4*)(cb + k * 256 + ch * 32);
                float4 A0 = cbp[0], A1 = cbp[1], A2 = cbp[2], A3 = cbp[3];
                float4 A4 = cbp[4], A5 = cbp[5], A6 = cbp[6], A7 = cbp[7];
                float Af[32] = {A0.x,A0.y,A0.z,A0.w, A1.x,A1.y,A1.z,A1.w,
                                A2.x,A2.y,A2.z,A2.w, A3.x,A3.y,A3.z,A3.w,
                                A4.x,A4.y,A4.z,A4.w, A5.x,A5.y,A5.z,A5.w,
                                A6.x,A6.y,A6.z,A6.w, A7.x,A7.y,A7.z,A7.w};
#pragma unroll
                for (int u = 0; u < 32; ++u)
                    sacc = __builtin_fmaf(zs[u][r], Af[u], sacc);
            }
        }
        if (active) {
            float d = z2w[n0 + r] - 2.0f * sacc;   // single rounding, d > 0
            unsigned long long key =
                ((unsigned long long)__float_as_uint(d) << 32) | (unsigned)k;
            atomicMin(&bestkey[n0 + r], key);
        }
    }
}

// ---------------------------------------------------------------------------
__global__ void vq_finalize_idx(const unsigned long long* __restrict__ bestkey,
                                int* __restrict__ idx, float* __restrict__ out_idx) {
    int n = blockIdx.x * 256 + threadIdx.x;
    int k = (int)(unsigned)(bestkey[n] & 0xFFFFFFFFu);
    idx[n] = k;
    out_idx[n] = (float)k;
}

// ---------------------------------------------------------------------------
// Scatter + loss, block = (b, i). z staged via LDS transpose (coalesced reads),
// out writes coalesced. out[b,i,j,k] = cb[idx[b*1024+j*32+(k>>3)]][(k&7)*32+i].
__global__ __launch_bounds__(256) void vq_scatter_loss(
        const float* __restrict__ z, const float* __restrict__ cb,
        const int* __restrict__ idx, float* __restrict__ out,
        float* __restrict__ loss_out) {
    __shared__ float zs2[256][33];
    __shared__ int idxs[1024];
    __shared__ float wsum[4];

    const int t = threadIdx.x;
    const int b = blockIdx.x >> 5, i = blockIdx.x & 31;

#pragma unroll
    for (int it = 0; it < 32; ++it) {
        int k = it * 8 + (t >> 5);
        zs2[k][t & 31] = z[b * 262144 + k * 1024 + i * 32 + (t & 31)];
    }
#pragma unroll
    for (int u = 0; u < 4; ++u)
        idxs[u * 256 + t] = idx[b * 1024 + u * 256 + t];
    __syncthreads();

    float lsum = 0.f;
    float* obase = out + b * 262144 + i * 8192;
#pragma unroll 4
    for (int j = 0; j < 32; ++j) {
        int e = idxs[j * 32 + (t >> 3)];
        float zq = cb[e * 256 + (t & 7) * 32 + i];
        float zp = zs2[t][j];
        obase[j * 256 + t] = zq;
        float d = zp - zq;
        lsum = __builtin_fmaf(d, d, lsum);
    }
#pragma unroll
    for (int off = 32; off >= 1; off >>= 1) lsum += __shfl_down(lsum, off, 64);
    int lane = t & 63, wv = t >> 6;
    if (lane == 0) wsum[wv] = lsum;
    __syncthreads();
    if (t == 0)
        atomicAdd(loss_out, (wsum[0] + wsum[1] + wsum[2] + wsum[3]) *
                            (1.25f / (float)NELEM));
}

// ---------------------------------------------------------------------------
extern "C" void kernel_launch(void* const* d_in, const int* in_sizes, int n_in,
                              void* d_out, int out_size, void* d_ws, size_t ws_size,
                              hipStream_t stream) {
    const float* z  = (const float*)d_in[0];
    const float* cb = (const float*)d_in[1];
    float* out = (float*)d_out;

    char* ws = (char*)d_ws;
    unsigned short* zbf2   = (unsigned short*)ws;
    unsigned short* cbbf2  = (unsigned short*)(ws + 8388608);
    unsigned long long* cand = (unsigned long long*)(ws + 12582912);
    float* z2w             = (float*)(ws + 29360128);
    int*   idx             = (int*)(ws + 29425664);
    unsigned* gmax         = (unsigned*)(ws + 29491200);
    unsigned* cnt          = (unsigned*)(ws + 29556736);
    unsigned long long* bestkey = (unsigned long long*)(ws + 29622272);

    hipMemsetAsync(ws + 29491200, 0, 131072, stream);     // gmax + cnt
    hipMemsetAsync(ws + 29622272, 0xFF, 131072, stream);  // bestkey
    hipMemsetAsync(out + NELEM, 0, 4, stream);            // loss accumulator

    vq_prep_z<<<NROWS / 128, 128, 0, stream>>>(z, z2w, zbf2);
    vq_prep_cb<<<KENT / 128, 256, 0, stream>>>(cb, cbbf2);

    vq_gemm<<<8192, 256, 0, stream>>>(zbf2, cbbf2, gmax, cnt, cand);

    vq_rescore<<<NROWS / 128, 256, 0, stream>>>(z, cb, z2w, gmax, cnt, cand, bestkey);

    vq_finalize_idx<<<NROWS / 256, 256, 0, stream>>>(bestkey, idx, out + NELEM + 1);

    vq_scatter_loss<<<512, 256, 0, stream>>>(z, cb, idx, out, out + NELEM);
}

// Round 6
// 305.098 us; speedup vs baseline: 3.5754x; 1.0742x over previous
//
#include <hip/hip_runtime.h>
#include <stdint.h>

// Problem constants
#define NROWS 16384   // B*H*W = 16*32*32
#define KENT  8192    // codebook entries
#define CDIM  256     // embedding dim
#define NELEM 4194304 // B*H*W*C elements of z / z_q

#define MARGIN 1.5e-4f   // >=30 sigma of bf16-screen error (rms ~3e-6)

// ws layout (bytes), total 29,622,272 (~28.25 MiB):
//   [0,        8388608): zbf2  u16[4M]   z bf16, k-major tile layout
//   [8388608, 12582912): cbbf2 u16[2M]   codebook bf16, same layout
//   [12582912,29360128): cand  u64[16384][128]  (score_bits<<32 | k)
//   [29360128,29425664): z2w   float[16384]
//   [29425664,29491200): idx   int[16384]
//   [29491200,29556736): gmax  u32[16384]  monotone row max   -- memset 0
//   [29556736,29622272): cnt   u32[16384]  candidate counts   -- memset 0

typedef short v8s __attribute__((ext_vector_type(8)));
typedef float v4f __attribute__((ext_vector_type(4)));

__device__ inline unsigned short f2bf_rne(float f) {
    unsigned b = __float_as_uint(f);
    return (unsigned short)((b + 0x7FFFu + ((b >> 16) & 1u)) >> 16);
}
__device__ inline unsigned mono(float f) {   // order-preserving float->u32
    unsigned b = __float_as_uint(f);
    return (b & 0x80000000u) ? ~b : (b | 0x80000000u);
}
__device__ inline float dmono(unsigned u) {
    unsigned b = (u & 0x80000000u) ? (u ^ 0x80000000u) : ~u;
    return __uint_as_float(b);
}
__device__ inline void gload_lds16(const void* g, void* l) {
    __builtin_amdgcn_global_load_lds(
        (const __attribute__((address_space(1))) void*)g,
        (__attribute__((address_space(3))) void*)l, 16, 0, 0);
}

// ---------------------------------------------------------------------------
// prep_z v2: 256 blocks x 128 threads; 2 threads per row (one per 128-c half
// of the VALIDATED np AVX512 pairwise tree). Register-only bf16 transpose,
// coalesced 16B stores, no LDS except a 64-float cross-wave combine.
__global__ __launch_bounds__(128) void vq_prep_z(
        const float* __restrict__ z, float* __restrict__ z2w,
        unsigned short* __restrict__ zbf2) {
    __shared__ float s64[64];
    const int t = threadIdx.x;
    const int r = t & 63;        // row within this 64-row slab
    const int blk = t >> 6;      // 0/1 = c-half (wave 0 / wave 1)
    const int n = blockIdx.x * 64 + r;
    const int b = n >> 10, hw = n & 1023;
    const float* base = z + b * 262144 + hw;

    float t0[16], p01[16], p0123[16], C[16];
    unsigned buf32[8][8];        // bf16 pairs: (j, L>>1), L even in low half

#pragma unroll
    for (int j = 0; j < 8; ++j) {
        float a[16];
#pragma unroll
        for (int L = 0; L < 16; ++L)
            a[L] = base[(blk * 128 + L + 16 * j) * 1024];
        unsigned lo = 0;
#pragma unroll
        for (int L = 0; L < 16; ++L) {
            unsigned short h = f2bf_rne(a[L]);
            if (L & 1) buf32[j][L >> 1] = lo | ((unsigned)h << 16);
            else       lo = h;
            float sq = a[L] * a[L];
            asm volatile("" : "+v"(sq));   // forbid FMA contraction into adds
            // np tree phases: C = ((q0+q1)+(q2+q3)) + ((q4+q5)+(q6+q7))
            if (j == 0 || j == 2 || j == 4 || j == 6) t0[L] = sq;
            else if (j == 1) p01[L] = t0[L] + sq;
            else if (j == 3) p0123[L] = p01[L] + (t0[L] + sq);
            else if (j == 5) p01[L] = t0[L] + sq;                 // reuse as p45
            else             C[L] = p0123[L] + (p01[L] + (t0[L] + sq));
        }
    }
    // _mm512_reduce_add_ps halving tree over lanes
    float t8[8];
#pragma unroll
    for (int L = 0; L < 8; ++L) t8[L] = C[L] + C[L + 8];
    float t4[4];
#pragma unroll
    for (int L = 0; L < 4; ++L) t4[L] = t8[L] + t8[L + 4];
    float t2a = t4[0] + t4[2];
    float t2b = t4[1] + t4[3];
    float bs = t2a + t2b;

    if (blk == 1) s64[r] = bs;
    __syncthreads();
    if (blk == 0) z2w[n] = bs + s64[r];

    // bf16 k-major tile store: chunk qg = blk*16+qq covers c = qg*8..+8
    const int p = n >> 7, rp = n & 127;
    unsigned short* dst = zbf2 + p * 32768;
#pragma unroll
    for (int qq = 0; qq < 16; ++qq) {
        uint4 v;
        v.x = buf32[qq >> 1][4 * (qq & 1) + 0];
        v.y = buf32[qq >> 1][4 * (qq & 1) + 1];
        v.z = buf32[qq >> 1][4 * (qq & 1) + 2];
        v.w = buf32[qq >> 1][4 * (qq & 1) + 3];
        *(uint4*)&dst[((blk * 16 + qq) * 128 + rp) * 8] = v;
    }
}

// ---------------------------------------------------------------------------
__global__ __launch_bounds__(256) void vq_prep_cb(
        const float* __restrict__ cb, unsigned short* __restrict__ cbbf2) {
    const int t = threadIdx.x, p = blockIdx.x, n0 = p * 128;
    unsigned short* dst = cbbf2 + p * 32768;
#pragma unroll
    for (int it = 0; it < 16; ++it) {
        int chunk = it * 256 + t;
        int q = chunk >> 7, r = chunk & 127;
        const float* src = cb + (n0 + r) * 256 + q * 8;
        float4 a = *(const float4*)src;
        float4 c = *(const float4*)(src + 4);
        uint4 v;
        v.x = (unsigned)f2bf_rne(a.x) | ((unsigned)f2bf_rne(a.y) << 16);
        v.y = (unsigned)f2bf_rne(a.z) | ((unsigned)f2bf_rne(a.w) << 16);
        v.z = (unsigned)f2bf_rne(c.x) | ((unsigned)f2bf_rne(c.y) << 16);
        v.w = (unsigned)f2bf_rne(c.z) | ((unsigned)f2bf_rne(c.w) << 16);
        *(uint4*)&dst[chunk * 8] = v;
    }
}

// ---------------------------------------------------------------------------
// bf16 MFMA screen, v3:
//  - whole A panel (64KB, K=256) staged to LDS in ONE step: single barrier
//    drain instead of 8.
//  - B fragments streamed straight from L2 to registers (contiguous 16B in
//    the k-major panel layout; panel stays L2-hot via the XCD swizzle).
//    K-loop has NO barriers -> MFMA/global-load interleave freely.
//  - epilogue: LDS-compacted candidate push, one global atomicAdd per row.
#define SMEM_AS    0        // 65536 B (A panel; aliased by lcand post-loop)
#define SMEM_RED2  65536    // 1024
#define SMEM_THL   66560    // 512
#define SMEM_LCNT  67072    // 512
#define SMEM_BASES 67584    // 512
#define SMEM_SZ    68096

__global__ __launch_bounds__(256, 2) void vq_gemm(
        const unsigned short* __restrict__ zbf2,
        const unsigned short* __restrict__ cbbf2,
        unsigned* __restrict__ gmax, unsigned* __restrict__ cnt,
        unsigned long long* __restrict__ cand) {
    __shared__ __align__(16) char smem[SMEM_SZ];
    short* As = (short*)(smem + SMEM_AS);
    float (*red2)[2] = (float(*)[2])(smem + SMEM_RED2);
    float* thL = (float*)(smem + SMEM_THL);
    unsigned* lcnt = (unsigned*)(smem + SMEM_LCNT);
    unsigned* bases = (unsigned*)(smem + SMEM_BASES);
    unsigned long long* lcand = (unsigned long long*)smem;  // aliases As

    const int tid = threadIdx.x;
    const int w = tid >> 6, l = tid & 63;
    const int q4 = l >> 4, cl = l & 15;
    const int mw = w & 1, nw = w >> 1;

    // XCD-locality swizzle (validated r5): 16 pm x phased 16 pn per XCD
    const unsigned bx = blockIdx.x;
    const unsigned xcd = bx & 7, local = bx >> 3;
    const unsigned png = local >> 8;
    const unsigned rem = local & 255;
    const unsigned pm = (rem >> 4) * 8 + xcd;
    const unsigned pn = png * 16 + (rem & 15);
    const int n0 = pm * 128;

    const char* Ab = (const char*)(zbf2 + pm * 32768);
    const char* Bb = (const char*)(cbbf2 + pn * 32768);

    // stage whole A panel: 16 issues x 256 thr x 16B = 64KB
#pragma unroll
    for (int u = 0; u < 16; ++u)
        gload_lds16(Ab + u * 4096 + tid * 16, smem + u * 4096 + (w << 10));

    v4f acc[4][4];
#pragma unroll
    for (int i = 0; i < 4; ++i)
#pragma unroll
        for (int j = 0; j < 4; ++j) acc[i][j] = (v4f)0.f;

    __syncthreads();   // single staging drain

    v8s bf[4], bfn[4];
#pragma unroll
    for (int j = 0; j < 4; ++j)
        bf[j] = *(const v8s*)(Bb + ((q4)*128 + nw * 64 + j * 16 + cl) * 16);

#pragma unroll
    for (int kt = 0; kt < 8; ++kt) {
        v8s af[4];
#pragma unroll
        for (int i = 0; i < 4; ++i)
            af[i] = *(const v8s*)&As[((kt * 4 + q4) * 128 + mw * 64 + i * 16 + cl) * 8];
        if (kt < 7) {
#pragma unroll
            for (int j = 0; j < 4; ++j)
                bfn[j] = *(const v8s*)(Bb +
                    (((kt + 1) * 4 + q4) * 128 + nw * 64 + j * 16 + cl) * 16);
        }
#pragma unroll
        for (int i = 0; i < 4; ++i)
#pragma unroll
            for (int j = 0; j < 4; ++j)
                acc[i][j] = __builtin_amdgcn_mfma_f32_16x16x32_bf16(
                    af[i], bf[j], acc[i][j], 0, 0, 0);
#pragma unroll
        for (int j = 0; j < 4; ++j) bf[j] = bfn[j];
    }

    // per-lane row maxes over this wave's 64 cols
    float pmx[4][4];
#pragma unroll
    for (int i = 0; i < 4; ++i) {
        v4f m = acc[i][0];
#pragma unroll
        for (int j = 1; j < 4; ++j) {
            m.x = fmaxf(m.x, acc[i][j].x); m.y = fmaxf(m.y, acc[i][j].y);
            m.z = fmaxf(m.z, acc[i][j].z); m.w = fmaxf(m.w, acc[i][j].w);
        }
        pmx[i][0] = m.x; pmx[i][1] = m.y; pmx[i][2] = m.z; pmx[i][3] = m.w;
#pragma unroll
        for (int g = 0; g < 4; ++g)
#pragma unroll
            for (int off = 1; off < 16; off <<= 1)
                pmx[i][g] = fmaxf(pmx[i][g], __shfl_xor(pmx[i][g], off));
    }
    __syncthreads();   // As reads done; smem reusable as lcand
    if (cl == 0) {
#pragma unroll
        for (int i = 0; i < 4; ++i)
#pragma unroll
            for (int g = 0; g < 4; ++g)
                red2[mw * 64 + i * 16 + q4 * 4 + g][nw] = pmx[i][g];
    }
    __syncthreads();
    if (tid < 128) {
        float bm = fmaxf(red2[tid][0], red2[tid][1]);
        atomicMax(&gmax[n0 + tid], mono(bm));
        thL[tid] = bm - MARGIN;
        lcnt[tid] = 0;
    }
    __syncthreads();

#pragma unroll
    for (int i = 0; i < 4; ++i)
#pragma unroll
        for (int g = 0; g < 4; ++g) {
            int r = mw * 64 + i * 16 + q4 * 4 + g;
            float th = thL[r];
#pragma unroll
            for (int j = 0; j < 4; ++j) {
                float s = acc[i][j][g];
                if (s >= th) {
                    unsigned slot = atomicAdd(&lcnt[r], 1u);
                    if (slot < 8u) {
                        unsigned k = pn * 128 + nw * 64 + j * 16 + cl;
                        lcand[r * 8 + slot] =
                            ((unsigned long long)__float_as_uint(s) << 32) | k;
                    }
                }
            }
        }
    __syncthreads();
    if (tid < 128) {
        unsigned m = lcnt[tid] < 8u ? lcnt[tid] : 8u;
        bases[tid] = atomicAdd(&cnt[n0 + tid], m);
    }
    __syncthreads();
#pragma unroll
    for (int e0 = 0; e0 < 1024; e0 += 256) {
        int e = e0 + tid;
        int r = e >> 3, s2 = e & 7;
        unsigned m = lcnt[r] < 8u ? lcnt[r] : 8u;
        if ((unsigned)s2 < m) {
            unsigned pos = bases[r] + (unsigned)s2;
            if (pos < 128u)
                cand[(unsigned)(n0 + r) * 128u + pos] = lcand[e];
        }
    }
}

// ---------------------------------------------------------------------------
// Exact rescore + finalize (rows are block-exclusive => LDS bestkey).
__global__ __launch_bounds__(256) void vq_rescore(
        const float* __restrict__ z, const float* __restrict__ cb,
        const float* __restrict__ z2w, const unsigned* __restrict__ gmax,
        const unsigned* __restrict__ cnt, const unsigned long long* __restrict__ cand,
        int* __restrict__ idx, float* __restrict__ out_idx) {
    __shared__ float zs[32][128];
    __shared__ float thrL[128];
    __shared__ unsigned short cntc[128];
    __shared__ unsigned candL[512];    // (r<<13)|k
    __shared__ unsigned blkcnt;
    __shared__ unsigned long long bestL[128];

    const int t = threadIdx.x;
    const int n0 = blockIdx.x * 128;
    const int b = n0 >> 10, hw0 = n0 & 1023;

    if (t < 128) {
        unsigned c = cnt[n0 + t];
        cntc[t] = (unsigned short)(c < 128u ? c : 128u);
        thrL[t] = dmono(gmax[n0 + t]) - MARGIN;
        bestL[t] = ~0ull;
    }
    if (t == 0) blkcnt = 0;
    __syncthreads();

    {   // filter: 2 threads per row scan its slots
        int r = t >> 1;
        int c = cntc[r];
        for (int s = (t & 1); s < c; s += 2) {
            unsigned long long e = cand[(unsigned)(n0 + r) * 128u + s];
            float sf = __uint_as_float((unsigned)(e >> 32));
            if (sf >= thrL[r]) {
                unsigned pos = atomicAdd(&blkcnt, 1u);
                if (pos < 512u)
                    candL[pos] = ((unsigned)r << 13) | (unsigned)(e & 0x1FFFu);
            }
        }
    }
    __syncthreads();
    int ns = (int)(blkcnt < 512u ? blkcnt : 512u);

    for (int base = 0; base < ns; base += 256) {
        bool active = base + t < ns;
        int r = 0, k = 0;
        if (active) {
            unsigned v = candL[base + t];
            r = v >> 13; k = v & 8191;
        }
        float sacc = 0.f;
        for (int ch = 0; ch < 8; ++ch) {
            __syncthreads();
            {   // stage 32 channels x 128 rows, coalesced
                int rr = t & 127, cc2 = t >> 7;
#pragma unroll
                for (int u = 0; u < 16; ++u) {
                    int cc = u * 2 + cc2;
                    zs[cc][rr] = z[b * 262144 + (ch * 32 + cc) * 1024 + hw0 + rr];
                }
            }
            __syncthreads();
            if (active) {
                const float4* cbp = (const float4*)(cb + k * 256 + ch * 32);
                float4 A0 = cbp[0], A1 = cbp[1], A2 = cbp[2], A3 = cbp[3];
                float4 A4 = cbp[4], A5 = cbp[5], A6 = cbp[6], A7 = cbp[7];
                float Af[32] = {A0.x,A0.y,A0.z,A0.w, A1.x,A1.y,A1.z,A1.w,
                                A2.x,A2.y,A2.z,A2.w, A3.x,A3.y,A3.z,A3.w,
                                A4.x,A4.y,A4.z,A4.w, A5.x,A5.y,A5.z,A5.w,
                                A6.x,A6.y,A6.z,A6.w, A7.x,A7.y,A7.z,A7.w};
#pragma unroll
                for (int u = 0; u < 32; ++u)
                    sacc = __builtin_fmaf(zs[u][r], Af[u], sacc);
            }
        }
        if (active) {
            float d = z2w[n0 + r] - 2.0f * sacc;   // single rounding, d > 0
            unsigned long long key =
                ((unsigned long long)__float_as_uint(d) << 32) | (unsigned)k;
            atomicMin(&bestL[r], key);
        }
    }
    __syncthreads();
    if (t < 128) {
        int k = (int)(unsigned)(bestL[t] & 0xFFFFFFFFu);
        idx[n0 + t] = k;
        out_idx[n0 + t] = (float)k;
    }
}

// ---------------------------------------------------------------------------
// Scatter + loss, block = (b, i). z staged via LDS transpose (coalesced reads),
// out writes coalesced. out[b,i,j,k] = cb[idx[b*1024+j*32+(k>>3)]][(k&7)*32+i].
__global__ __launch_bounds__(256) void vq_scatter_loss(
        const float* __restrict__ z, const float* __restrict__ cb,
        const int* __restrict__ idx, float* __restrict__ out,
        float* __restrict__ loss_out) {
    __shared__ float zs2[256][33];
    __shared__ int idxs[1024];
    __shared__ float wsum[4];

    const int t = threadIdx.x;
    const int b = blockIdx.x >> 5, i = blockIdx.x & 31;

#pragma unroll
    for (int it = 0; it < 32; ++it) {
        int k = it * 8 + (t >> 5);
        zs2[k][t & 31] = z[b * 262144 + k * 1024 + i * 32 + (t & 31)];
    }
#pragma unroll
    for (int u = 0; u < 4; ++u)
        idxs[u * 256 + t] = idx[b * 1024 + u * 256 + t];
    __syncthreads();

    float lsum = 0.f;
    float* obase = out + b * 262144 + i * 8192;
#pragma unroll 4
    for (int j = 0; j < 32; ++j) {
        int e = idxs[j * 32 + (t >> 3)];
        float zq = cb[e * 256 + (t & 7) * 32 + i];
        float zp = zs2[t][j];
        obase[j * 256 + t] = zq;
        float d = zp - zq;
        lsum = __builtin_fmaf(d, d, lsum);
    }
#pragma unroll
    for (int off = 32; off >= 1; off >>= 1) lsum += __shfl_down(lsum, off, 64);
    int lane = t & 63, wv = t >> 6;
    if (lane == 0) wsum[wv] = lsum;
    __syncthreads();
    if (t == 0)
        atomicAdd(loss_out, (wsum[0] + wsum[1] + wsum[2] + wsum[3]) *
                            (1.25f / (float)NELEM));
}

// ---------------------------------------------------------------------------
extern "C" void kernel_launch(void* const* d_in, const int* in_sizes, int n_in,
                              void* d_out, int out_size, void* d_ws, size_t ws_size,
                              hipStream_t stream) {
    const float* z  = (const float*)d_in[0];
    const float* cb = (const float*)d_in[1];
    float* out = (float*)d_out;

    char* ws = (char*)d_ws;
    unsigned short* zbf2   = (unsigned short*)ws;
    unsigned short* cbbf2  = (unsigned short*)(ws + 8388608);
    unsigned long long* cand = (unsigned long long*)(ws + 12582912);
    float* z2w             = (float*)(ws + 29360128);
    int*   idx             = (int*)(ws + 29425664);
    unsigned* gmax         = (unsigned*)(ws + 29491200);
    unsigned* cnt          = (unsigned*)(ws + 29556736);

    hipMemsetAsync(ws + 29491200, 0, 131072, stream);     // gmax + cnt
    hipMemsetAsync(out + NELEM, 0, 4, stream);            // loss accumulator

    vq_prep_z<<<NROWS / 64, 128, 0, stream>>>(z, z2w, zbf2);
    vq_prep_cb<<<KENT / 128, 256, 0, stream>>>(cb, cbbf2);

    vq_gemm<<<8192, 256, 0, stream>>>(zbf2, cbbf2, gmax, cnt, cand);

    vq_rescore<<<NROWS / 128, 256, 0, stream>>>(z, cb, z2w, gmax, cnt, cand,
                                                idx, out + NELEM + 1);

    vq_scatter_loss<<<512, 256, 0, stream>>>(z, cb, idx, out, out + NELEM);
}

// Round 7
// 250.009 us; speedup vs baseline: 4.3632x; 1.2203x over previous
//
#include <hip/hip_runtime.h>
#include <stdint.h>

// Problem constants
#define NROWS 16384   // B*H*W = 16*32*32
#define KENT  8192    // codebook entries
#define CDIM  256     // embedding dim
#define NELEM 4194304 // B*H*W*C elements of z / z_q

#define MARGIN 1.5e-4f   // >=30 sigma of bf16-screen error (rms ~3e-6)

// ws layout (bytes), total 29,622,272 (~28.25 MiB):
//   [0,        8388608): zbf2  u16[4M]   z bf16, k-major tile layout
//   [8388608, 12582912): cbbf2 u16[2M]   codebook bf16, same layout
//   [12582912,29360128): cand  u64[16384][128]  (score_bits<<32 | k)
//   [29360128,29425664): z2w   float[16384]
//   [29425664,29491200): idx   int[16384]
//   [29491200,29556736): gmax  u32[16384]  monotone row max   -- zeroed by prep
//   [29556736,29622272): cnt   u32[16384]  candidate counts   -- zeroed by prep

typedef short v8s __attribute__((ext_vector_type(8)));
typedef float v4f __attribute__((ext_vector_type(4)));

__device__ inline unsigned short f2bf_rne(float f) {
    unsigned b = __float_as_uint(f);
    return (unsigned short)((b + 0x7FFFu + ((b >> 16) & 1u)) >> 16);
}
__device__ inline unsigned mono(float f) {   // order-preserving float->u32
    unsigned b = __float_as_uint(f);
    return (b & 0x80000000u) ? ~b : (b | 0x80000000u);
}
__device__ inline float dmono(unsigned u) {
    unsigned b = (u & 0x80000000u) ? (u ^ 0x80000000u) : ~u;
    return __uint_as_float(b);
}
__device__ inline void gload_lds16(const void* g, void* l) {
    __builtin_amdgcn_global_load_lds(
        (const __attribute__((address_space(1))) void*)g,
        (__attribute__((address_space(3))) void*)l, 16, 0, 0);
}

// ---------------------------------------------------------------------------
// Fused prep: blocks 0..255 = prep_z (np-tree z2 + bf16 tile transpose),
// blocks 256..319 = prep_cb, plus zeroing of gmax/cnt/loss (kills 3 graph
// nodes: 2 memsets + 1 kernel). 128 threads everywhere.
__global__ __launch_bounds__(128) void vq_prep(
        const float* __restrict__ z, const float* __restrict__ cb,
        float* __restrict__ z2w, unsigned short* __restrict__ zbf2,
        unsigned short* __restrict__ cbbf2,
        unsigned* __restrict__ gmax, unsigned* __restrict__ cnt,
        float* __restrict__ loss_out) {
    const int t = threadIdx.x;
    const int bid = blockIdx.x;

    if (bid >= 256) {   // ---- prep_cb: panel p = bid-256
        const int p = bid - 256, n0 = p * 128;
        unsigned short* dst = cbbf2 + p * 32768;
        // q = it, r = t: per-thread one codebook row, 32 contiguous 32B reads
        const float* src = cb + (n0 + t) * 256;
#pragma unroll
        for (int q = 0; q < 32; ++q) {
            float4 a = *(const float4*)(src + q * 8);
            float4 c = *(const float4*)(src + q * 8 + 4);
            uint4 v;
            v.x = (unsigned)f2bf_rne(a.x) | ((unsigned)f2bf_rne(a.y) << 16);
            v.y = (unsigned)f2bf_rne(a.z) | ((unsigned)f2bf_rne(a.w) << 16);
            v.z = (unsigned)f2bf_rne(c.x) | ((unsigned)f2bf_rne(c.y) << 16);
            v.w = (unsigned)f2bf_rne(c.z) | ((unsigned)f2bf_rne(c.w) << 16);
            *(uint4*)&dst[(q * 128 + t) * 8] = v;
        }
        if (p == 0 && t == 0) loss_out[0] = 0.f;
        return;
    }

    // ---- prep_z (validated r6): 2 threads/row, one per 128-c np-tree half
    __shared__ float s64[64];
    const int r = t & 63;
    const int blk = t >> 6;
    const int n = bid * 64 + r;
    const int b = n >> 10, hw = n & 1023;
    const float* base = z + b * 262144 + hw;

    // zero gmax/cnt slices (64 rows per block)
    if (blk == 0) gmax[bid * 64 + r] = 0u;
    else          cnt[bid * 64 + r] = 0u;

    float t0[16], p01[16], p0123[16], C[16];
    unsigned buf32[8][8];

#pragma unroll
    for (int j = 0; j < 8; ++j) {
        float a[16];
#pragma unroll
        for (int L = 0; L < 16; ++L)
            a[L] = base[(blk * 128 + L + 16 * j) * 1024];
        unsigned lo = 0;
#pragma unroll
        for (int L = 0; L < 16; ++L) {
            unsigned short h = f2bf_rne(a[L]);
            if (L & 1) buf32[j][L >> 1] = lo | ((unsigned)h << 16);
            else       lo = h;
            float sq = a[L] * a[L];
            asm volatile("" : "+v"(sq));   // forbid FMA contraction into adds
            if (j == 0 || j == 2 || j == 4 || j == 6) t0[L] = sq;
            else if (j == 1) p01[L] = t0[L] + sq;
            else if (j == 3) p0123[L] = p01[L] + (t0[L] + sq);
            else if (j == 5) p01[L] = t0[L] + sq;                 // p45
            else             C[L] = p0123[L] + (p01[L] + (t0[L] + sq));
        }
    }
    float t8[8];
#pragma unroll
    for (int L = 0; L < 8; ++L) t8[L] = C[L] + C[L + 8];
    float t4[4];
#pragma unroll
    for (int L = 0; L < 4; ++L) t4[L] = t8[L] + t8[L + 4];
    float t2a = t4[0] + t4[2];
    float t2b = t4[1] + t4[3];
    float bs = t2a + t2b;

    if (blk == 1) s64[r] = bs;
    __syncthreads();
    if (blk == 0) z2w[n] = bs + s64[r];

    const int p = n >> 7, rp = n & 127;
    unsigned short* dst = zbf2 + p * 32768;
#pragma unroll
    for (int qq = 0; qq < 16; ++qq) {
        uint4 v;
        v.x = buf32[qq >> 1][4 * (qq & 1) + 0];
        v.y = buf32[qq >> 1][4 * (qq & 1) + 1];
        v.z = buf32[qq >> 1][4 * (qq & 1) + 2];
        v.w = buf32[qq >> 1][4 * (qq & 1) + 3];
        *(uint4*)&dst[((blk * 16 + qq) * 128 + rp) * 8] = v;
    }
}

// ---------------------------------------------------------------------------
// bf16 MFMA screen, v4 = r5 structure (validated 130us, 4 blocks/CU) +
// BK=32 double-buffered prefetch: stage s+1 loads issue right after the
// barrier opening stage s -> one barrier per stage (8 vs 15) and each
// load has a full compute stage in flight before the vmcnt drain.
#define SMEM_BUF0  0        // 16384: A(8K) + B(8K), stage buffer 0
#define SMEM_BUF1  16384    // 16384: stage buffer 1
#define SMEM_RED2  32768    // 1024
#define SMEM_THL   33792    // 512
#define SMEM_LCNT  34304    // 512
#define SMEM_BASES 34816    // 512
#define SMEM_SZ    35328

__global__ __launch_bounds__(256, 4) void vq_gemm(
        const unsigned short* __restrict__ zbf2,
        const unsigned short* __restrict__ cbbf2,
        unsigned* __restrict__ gmax, unsigned* __restrict__ cnt,
        unsigned long long* __restrict__ cand) {
    __shared__ __align__(16) char smem[SMEM_SZ];
    float (*red2)[2] = (float(*)[2])(smem + SMEM_RED2);
    float* thL = (float*)(smem + SMEM_THL);
    unsigned* lcnt = (unsigned*)(smem + SMEM_LCNT);
    unsigned* bases = (unsigned*)(smem + SMEM_BASES);
    unsigned long long* lcand = (unsigned long long*)smem;  // aliases buf0

    const int tid = threadIdx.x;
    const int w = tid >> 6, l = tid & 63;
    const int q4 = l >> 4, cl = l & 15;
    const int mw = w & 1, nw = w >> 1;

    // XCD-locality swizzle (validated r5): 16 pm x phased 16 pn per XCD
    const unsigned bx = blockIdx.x;
    const unsigned xcd = bx & 7, local = bx >> 3;
    const unsigned png = local >> 8;
    const unsigned rem = local & 255;
    const unsigned pm = (rem >> 4) * 8 + xcd;
    const unsigned pn = png * 16 + (rem & 15);
    const int n0 = pm * 128;

    const char* Ab = (const char*)(zbf2 + pm * 32768);
    const char* Bb = (const char*)(cbbf2 + pn * 32768);

    // prologue: stage 0 -> buf0 (per stage: 8KB A + 8KB B, 4 issues/thread)
    {
        char* d = smem + SMEM_BUF0;
#pragma unroll
        for (int u = 0; u < 2; ++u) {
            gload_lds16(Ab + u * 4096 + tid * 16, d + u * 4096 + (w << 10));
            gload_lds16(Bb + u * 4096 + tid * 16, d + 8192 + u * 4096 + (w << 10));
        }
    }

    v4f acc[4][4];
#pragma unroll
    for (int i = 0; i < 4; ++i)
#pragma unroll
        for (int j = 0; j < 4; ++j) acc[i][j] = (v4f)0.f;

    __syncthreads();   // drain stage 0

#pragma unroll
    for (int s = 0; s < 8; ++s) {
        if (s < 7) {   // prefetch next stage into the other buffer
            char* d = smem + ((s + 1) & 1) * 16384;
#pragma unroll
            for (int u = 0; u < 2; ++u) {
                gload_lds16(Ab + (s + 1) * 8192 + u * 4096 + tid * 16,
                            d + u * 4096 + (w << 10));
                gload_lds16(Bb + (s + 1) * 8192 + u * 4096 + tid * 16,
                            d + 8192 + u * 4096 + (w << 10));
            }
        }
        const short* As_ = (const short*)(smem + (s & 1) * 16384);
        const short* Bs_ = (const short*)(smem + (s & 1) * 16384 + 8192);
        v8s af[4], bf[4];
#pragma unroll
        for (int i = 0; i < 4; ++i)
            af[i] = *(const v8s*)&As_[(q4 * 128 + mw * 64 + i * 16 + cl) * 8];
#pragma unroll
        for (int j = 0; j < 4; ++j)
            bf[j] = *(const v8s*)&Bs_[(q4 * 128 + nw * 64 + j * 16 + cl) * 8];
#pragma unroll
        for (int i = 0; i < 4; ++i)
#pragma unroll
            for (int j = 0; j < 4; ++j)
                acc[i][j] = __builtin_amdgcn_mfma_f32_16x16x32_bf16(
                    af[i], bf[j], acc[i][j], 0, 0, 0);
        __syncthreads();   // drains prefetch; protects buffer swap
    }

    // per-lane row maxes over this wave's 64 cols
    float pmx[4][4];
#pragma unroll
    for (int i = 0; i < 4; ++i) {
        v4f m = acc[i][0];
#pragma unroll
        for (int j = 1; j < 4; ++j) {
            m.x = fmaxf(m.x, acc[i][j].x); m.y = fmaxf(m.y, acc[i][j].y);
            m.z = fmaxf(m.z, acc[i][j].z); m.w = fmaxf(m.w, acc[i][j].w);
        }
        pmx[i][0] = m.x; pmx[i][1] = m.y; pmx[i][2] = m.z; pmx[i][3] = m.w;
#pragma unroll
        for (int g = 0; g < 4; ++g)
#pragma unroll
            for (int off = 1; off < 16; off <<= 1)
                pmx[i][g] = fmaxf(pmx[i][g], __shfl_xor(pmx[i][g], off));
    }
    if (cl == 0) {
#pragma unroll
        for (int i = 0; i < 4; ++i)
#pragma unroll
            for (int g = 0; g < 4; ++g)
                red2[mw * 64 + i * 16 + q4 * 4 + g][nw] = pmx[i][g];
    }
    __syncthreads();
    if (tid < 128) {
        float bm = fmaxf(red2[tid][0], red2[tid][1]);
        atomicMax(&gmax[n0 + tid], mono(bm));
        thL[tid] = bm - MARGIN;
        lcnt[tid] = 0;
    }
    __syncthreads();

    // compact candidate push into LDS, then one global atomicAdd per row
#pragma unroll
    for (int i = 0; i < 4; ++i)
#pragma unroll
        for (int g = 0; g < 4; ++g) {
            int r = mw * 64 + i * 16 + q4 * 4 + g;
            float th = thL[r];
#pragma unroll
            for (int j = 0; j < 4; ++j) {
                float s = acc[i][j][g];
                if (s >= th) {
                    unsigned slot = atomicAdd(&lcnt[r], 1u);
                    if (slot < 8u) {
                        unsigned k = pn * 128 + nw * 64 + j * 16 + cl;
                        lcand[r * 8 + slot] =
                            ((unsigned long long)__float_as_uint(s) << 32) | k;
                    }
                }
            }
        }
    __syncthreads();
    if (tid < 128) {
        unsigned m = lcnt[tid] < 8u ? lcnt[tid] : 8u;
        bases[tid] = atomicAdd(&cnt[n0 + tid], m);
    }
    __syncthreads();
#pragma unroll
    for (int e0 = 0; e0 < 1024; e0 += 256) {
        int e = e0 + tid;
        int r = e >> 3, s2 = e & 7;
        unsigned m = lcnt[r] < 8u ? lcnt[r] : 8u;
        if ((unsigned)s2 < m) {
            unsigned pos = bases[r] + (unsigned)s2;
            if (pos < 128u)
                cand[(unsigned)(n0 + r) * 128u + pos] = lcand[e];
        }
    }
}

// ---------------------------------------------------------------------------
// Exact rescore + finalize (rows are block-exclusive => LDS bestkey).
__global__ __launch_bounds__(256) void vq_rescore(
        const float* __restrict__ z, const float* __restrict__ cb,
        const float* __restrict__ z2w, const unsigned* __restrict__ gmax,
        const unsigned* __restrict__ cnt, const unsigned long long* __restrict__ cand,
        int* __restrict__ idx, float* __restrict__ out_idx) {
    __shared__ float zs[32][128];
    __shared__ float thrL[128];
    __shared__ unsigned short cntc[128];
    __shared__ unsigned candL[512];    // (r<<13)|k
    __shared__ unsigned blkcnt;
    __shared__ unsigned long long bestL[128];

    const int t = threadIdx.x;
    const int n0 = blockIdx.x * 128;
    const int b = n0 >> 10, hw0 = n0 & 1023;

    if (t < 128) {
        unsigned c = cnt[n0 + t];
        cntc[t] = (unsigned short)(c < 128u ? c : 128u);
        thrL[t] = dmono(gmax[n0 + t]) - MARGIN;
        bestL[t] = ~0ull;
    }
    if (t == 0) blkcnt = 0;
    __syncthreads();

    {   // filter: 2 threads per row scan its slots
        int r = t >> 1;
        int c = cntc[r];
        for (int s = (t & 1); s < c; s += 2) {
            unsigned long long e = cand[(unsigned)(n0 + r) * 128u + s];
            float sf = __uint_as_float((unsigned)(e >> 32));
            if (sf >= thrL[r]) {
                unsigned pos = atomicAdd(&blkcnt, 1u);
                if (pos < 512u)
                    candL[pos] = ((unsigned)r << 13) | (unsigned)(e & 0x1FFFu);
            }
        }
    }
    __syncthreads();
    int ns = (int)(blkcnt < 512u ? blkcnt : 512u);

    for (int base = 0; base < ns; base += 256) {
        bool active = base + t < ns;
        int r = 0, k = 0;
        if (active) {
            unsigned v = candL[base + t];
            r = v >> 13; k = v & 8191;
        }
        float sacc = 0.f;
        for (int ch = 0; ch < 8; ++ch) {
            __syncthreads();
            {   // stage 32 channels x 128 rows, coalesced
                int rr = t & 127, cc2 = t >> 7;
#pragma unroll
                for (int u = 0; u < 16; ++u) {
                    int cc = u * 2 + cc2;
                    zs[cc][rr] = z[b * 262144 + (ch * 32 + cc) * 1024 + hw0 + rr];
                }
            }
            __syncthreads();
            if (active) {
                const float4* cbp = (const float4*)(cb + k * 256 + ch * 32);
                float4 A0 = cbp[0], A1 = cbp[1], A2 = cbp[2], A3 = cbp[3];
                float4 A4 = cbp[4], A5 = cbp[5], A6 = cbp[6], A7 = cbp[7];
                float Af[32] = {A0.x,A0.y,A0.z,A0.w, A1.x,A1.y,A1.z,A1.w,
                                A2.x,A2.y,A2.z,A2.w, A3.x,A3.y,A3.z,A3.w,
                                A4.x,A4.y,A4.z,A4.w, A5.x,A5.y,A5.z,A5.w,
                                A6.x,A6.y,A6.z,A6.w, A7.x,A7.y,A7.z,A7.w};
#pragma unroll
                for (int u = 0; u < 32; ++u)
                    sacc = __builtin_fmaf(zs[u][r], Af[u], sacc);
            }
        }
        if (active) {
            float d = z2w[n0 + r] - 2.0f * sacc;   // single rounding, d > 0
            unsigned long long key =
                ((unsigned long long)__float_as_uint(d) << 32) | (unsigned)k;
            atomicMin(&bestL[r], key);
        }
    }
    __syncthreads();
    if (t < 128) {
        int k = (int)(unsigned)(bestL[t] & 0xFFFFFFFFu);
        idx[n0 + t] = k;
        out_idx[n0 + t] = (float)k;
    }
}

// ---------------------------------------------------------------------------
// Scatter + loss, block = (b, i). z staged via LDS transpose (coalesced reads),
// out writes coalesced. out[b,i,j,k] = cb[idx[b*1024+j*32+(k>>3)]][(k&7)*32+i].
__global__ __launch_bounds__(256) void vq_scatter_loss(
        const float* __restrict__ z, const float* __restrict__ cb,
        const int* __restrict__ idx, float* __restrict__ out,
        float* __restrict__ loss_out) {
    __shared__ float zs2[256][33];
    __shared__ int idxs[1024];
    __shared__ float wsum[4];

    const int t = threadIdx.x;
    const int b = blockIdx.x >> 5, i = blockIdx.x & 31;

#pragma unroll
    for (int it = 0; it < 32; ++it) {
        int k = it * 8 + (t >> 5);
        zs2[k][t & 31] = z[b * 262144 + k * 1024 + i * 32 + (t & 31)];
    }
#pragma unroll
    for (int u = 0; u < 4; ++u)
        idxs[u * 256 + t] = idx[b * 1024 + u * 256 + t];
    __syncthreads();

    float lsum = 0.f;
    float* obase = out + b * 262144 + i * 8192;
#pragma unroll 4
    for (int j = 0; j < 32; ++j) {
        int e = idxs[j * 32 + (t >> 3)];
        float zq = cb[e * 256 + (t & 7) * 32 + i];
        float zp = zs2[t][j];
        obase[j * 256 + t] = zq;
        float d = zp - zq;
        lsum = __builtin_fmaf(d, d, lsum);
    }
#pragma unroll
    for (int off = 32; off >= 1; off >>= 1) lsum += __shfl_down(lsum, off, 64);
    int lane = t & 63, wv = t >> 6;
    if (lane == 0) wsum[wv] = lsum;
    __syncthreads();
    if (t == 0)
        atomicAdd(loss_out, (wsum[0] + wsum[1] + wsum[2] + wsum[3]) *
                            (1.25f / (float)NELEM));
}

// ---------------------------------------------------------------------------
extern "C" void kernel_launch(void* const* d_in, const int* in_sizes, int n_in,
                              void* d_out, int out_size, void* d_ws, size_t ws_size,
                              hipStream_t stream) {
    const float* z  = (const float*)d_in[0];
    const float* cb = (const float*)d_in[1];
    float* out = (float*)d_out;

    char* ws = (char*)d_ws;
    unsigned short* zbf2   = (unsigned short*)ws;
    unsigned short* cbbf2  = (unsigned short*)(ws + 8388608);
    unsigned long long* cand = (unsigned long long*)(ws + 12582912);
    float* z2w             = (float*)(ws + 29360128);
    int*   idx             = (int*)(ws + 29425664);
    unsigned* gmax         = (unsigned*)(ws + 29491200);
    unsigned* cnt          = (unsigned*)(ws + 29556736);

    vq_prep<<<320, 128, 0, stream>>>(z, cb, z2w, zbf2, cbbf2,
                                     gmax, cnt, out + NELEM);

    vq_gemm<<<8192, 256, 0, stream>>>(zbf2, cbbf2, gmax, cnt, cand);

    vq_rescore<<<NROWS / 128, 256, 0, stream>>>(z, cb, z2w, gmax, cnt, cand,
                                                idx, out + NELEM + 1);

    vq_scatter_loss<<<512, 256, 0, stream>>>(z, cb, idx, out, out + NELEM);
}

// Round 8
// 231.322 us; speedup vs baseline: 4.7157x; 1.0808x over previous
//
#include <hip/hip_runtime.h>
#include <stdint.h>

// Problem constants
#define NROWS 16384   // B*H*W = 16*32*32
#define KENT  8192    // codebook entries
#define CDIM  256     // embedding dim
#define NELEM 4194304 // B*H*W*C elements of z / z_q

// int8 screen scales: z*22 (clamp +-127 = 5.77 sigma), cb*127*8192 (<=0.5 LSB)
#define ZSCALE 22.0f
#define ESCALE 1040384.0f      // 127*8192, exact in fp32
#define MARGIN_INT 4096        // = 1.79e-4 real ~ 8 sigma of i8-quant error
#define MARGIN_REAL 1.79e-4f

// ws layout (bytes), total 23,330,816 (~22.25 MiB):
//   [0,        4194304): zbi8  i8[4M]   z int8, k-major tile layout
//   [4194304,  6291456): cbi8  i8[2M]   codebook int8, same layout
//   [6291456, 23068672): cand  u64[16384][128]  (score_int<<32 | k)
//   [23068672,23134208): z2w   float[16384]  np-tree row norms
//   [23134208,23199744): idx   int[16384]
//   [23199744,23265280): gmax  i32[16384] row max score  -- init INT_MIN by prep
//   [23265280,23330816): cnt   u32[16384] candidate counts -- zeroed by prep
//
// i8 tile layout: panel p = row>>7, chunk q = c>>4 (16 bytes of c), byte:
//   p*32768 + (q*128 + (row&127))*16 + (c&15)
// => GEMM stage s (k0=s*64) reads panel bytes [s*8192, +8192) contiguous,
//    and each lane's A/B fragment (16 contiguous k-bytes) is one b128 read.

typedef int v4i __attribute__((ext_vector_type(4)));

__device__ inline int q8(float x, float s) {
    int v = __float2int_rn(x * s);
    return v < -127 ? -127 : (v > 127 ? 127 : v);
}
__device__ inline unsigned pk4(int a, int b, int c, int d) {
    return (a & 255) | ((b & 255) << 8) | ((c & 255) << 16) | ((d & 255) << 24);
}
__device__ inline void gload_lds16(const void* g, void* l) {
    __builtin_amdgcn_global_load_lds(
        (const __attribute__((address_space(1))) void*)g,
        (__attribute__((address_space(3))) void*)l, 16, 0, 0);
}

// ---------------------------------------------------------------------------
// Fused prep: blocks 0..255 = prep_z (VALIDATED np-tree z2 + i8 tile store),
// blocks 256..319 = prep_cb (i8), plus gmax/cnt/loss init.
__global__ __launch_bounds__(128) void vq_prep(
        const float* __restrict__ z, const float* __restrict__ cb,
        float* __restrict__ z2w, char* __restrict__ zbi8,
        char* __restrict__ cbbi8,
        int* __restrict__ gmax, unsigned* __restrict__ cnt,
        float* __restrict__ loss_out) {
    const int t = threadIdx.x;
    const int bid = blockIdx.x;

    if (bid >= 256) {   // ---- prep_cb: panel p, one codebook row per thread
        const int p = bid - 256, n0 = p * 128;
        char* dst = cbbi8 + p * 32768;
        const float* src = cb + (n0 + t) * 256;
#pragma unroll
        for (int q = 0; q < 16; ++q) {
            float4 a = *(const float4*)(src + q * 16);
            float4 b = *(const float4*)(src + q * 16 + 4);
            float4 c = *(const float4*)(src + q * 16 + 8);
            float4 d = *(const float4*)(src + q * 16 + 12);
            uint4 v;
            v.x = pk4(q8(a.x,ESCALE), q8(a.y,ESCALE), q8(a.z,ESCALE), q8(a.w,ESCALE));
            v.y = pk4(q8(b.x,ESCALE), q8(b.y,ESCALE), q8(b.z,ESCALE), q8(b.w,ESCALE));
            v.z = pk4(q8(c.x,ESCALE), q8(c.y,ESCALE), q8(c.z,ESCALE), q8(c.w,ESCALE));
            v.w = pk4(q8(d.x,ESCALE), q8(d.y,ESCALE), q8(d.z,ESCALE), q8(d.w,ESCALE));
            *(uint4*)&dst[(q * 128 + t) * 16] = v;
        }
        if (p == 0 && t == 0) loss_out[0] = 0.f;
        return;
    }

    // ---- prep_z: 2 threads/row, one per 128-c half of the np tree
    __shared__ float s64[64];
    const int r = t & 63;
    const int blk = t >> 6;
    const int n = bid * 64 + r;
    const int b = n >> 10, hw = n & 1023;
    const float* base = z + b * 262144 + hw;

    if (blk == 0) gmax[bid * 64 + r] = (int)0x80000000;   // INT_MIN
    else          cnt[bid * 64 + r] = 0u;

    const int p = n >> 7, rp = n & 127;
    char* dst = zbi8 + p * 32768;

    float t0[16], p01[16], p0123[16], C[16];

#pragma unroll
    for (int j = 0; j < 8; ++j) {
        float a[16];
#pragma unroll
        for (int L = 0; L < 16; ++L)
            a[L] = base[(blk * 128 + L + 16 * j) * 1024];
        int qb[16];
#pragma unroll
        for (int L = 0; L < 16; ++L) {
            qb[L] = q8(a[L], ZSCALE);
            float sq = a[L] * a[L];
            asm volatile("" : "+v"(sq));   // forbid FMA contraction into adds
            // np tree phases: C = ((q0+q1)+(q2+q3)) + ((q4+q5)+(q6+q7))
            if (j == 0 || j == 2 || j == 4 || j == 6) t0[L] = sq;
            else if (j == 1) p01[L] = t0[L] + sq;
            else if (j == 3) p0123[L] = p01[L] + (t0[L] + sq);
            else if (j == 5) p01[L] = t0[L] + sq;                 // p45
            else             C[L] = p0123[L] + (p01[L] + (t0[L] + sq));
        }
        // chunk q_g = blk*8 + j holds channels c = blk*128 + 16j + L
        uint4 v;
        v.x = pk4(qb[0], qb[1], qb[2], qb[3]);
        v.y = pk4(qb[4], qb[5], qb[6], qb[7]);
        v.z = pk4(qb[8], qb[9], qb[10], qb[11]);
        v.w = pk4(qb[12], qb[13], qb[14], qb[15]);
        *(uint4*)&dst[((blk * 8 + j) * 128 + rp) * 16] = v;
    }
    float t8[8];
#pragma unroll
    for (int L = 0; L < 8; ++L) t8[L] = C[L] + C[L + 8];
    float t4[4];
#pragma unroll
    for (int L = 0; L < 4; ++L) t4[L] = t8[L] + t8[L + 4];
    float t2a = t4[0] + t4[2];
    float t2b = t4[1] + t4[3];
    float bs = t2a + t2b;

    if (blk == 1) s64[r] = bs;
    __syncthreads();
    if (blk == 0) z2w[n] = bs + s64[r];
}

// ---------------------------------------------------------------------------
// int8 MFMA screen: r7 structure (XCD swizzle, dbuf, 4 blocks/CU) but
// mfma_i32_16x16x64_i8 -> 4 stages of BK=64, half the MFMA instructions,
// half the LDS/staging/L2 bytes of the bf16 version. Integer epilogue.
#define SMEM_BUF0  0        // 16384: A(8K) + B(8K), stage buffer 0
#define SMEM_BUF1  16384    // 16384: stage buffer 1
#define SMEM_RED2  32768    // 1024
#define SMEM_THL   33792    // 512
#define SMEM_LCNT  34304    // 512
#define SMEM_BASES 34816    // 512
#define SMEM_SZ    35328

__global__ __launch_bounds__(256, 4) void vq_gemm(
        const char* __restrict__ zbi8,
        const char* __restrict__ cbbi8,
        int* __restrict__ gmax, unsigned* __restrict__ cnt,
        unsigned long long* __restrict__ cand) {
    __shared__ __align__(16) char smem[SMEM_SZ];
    int (*red2)[2] = (int(*)[2])(smem + SMEM_RED2);
    int* thL = (int*)(smem + SMEM_THL);
    unsigned* lcnt = (unsigned*)(smem + SMEM_LCNT);
    unsigned* bases = (unsigned*)(smem + SMEM_BASES);
    unsigned long long* lcand = (unsigned long long*)smem;  // aliases buf0

    const int tid = threadIdx.x;
    const int w = tid >> 6, l = tid & 63;
    const int q4 = l >> 4, cl = l & 15;
    const int mw = w & 1, nw = w >> 1;

    // XCD-locality swizzle (validated r5): 16 pm x phased 16 pn per XCD
    const unsigned bx = blockIdx.x;
    const unsigned xcd = bx & 7, local = bx >> 3;
    const unsigned png = local >> 8;
    const unsigned rem = local & 255;
    const unsigned pm = (rem >> 4) * 8 + xcd;
    const unsigned pn = png * 16 + (rem & 15);
    const int n0 = pm * 128;

    const char* Ab = zbi8 + pm * 32768;
    const char* Bb = cbbi8 + pn * 32768;

    // prologue: stage 0 -> buf0 (A 8KB + B 8KB)
    {
        char* d = smem + SMEM_BUF0;
#pragma unroll
        for (int u = 0; u < 2; ++u) {
            gload_lds16(Ab + u * 4096 + tid * 16, d + u * 4096 + (w << 10));
            gload_lds16(Bb + u * 4096 + tid * 16, d + 8192 + u * 4096 + (w << 10));
        }
    }

    v4i acc[4][4];
#pragma unroll
    for (int i = 0; i < 4; ++i)
#pragma unroll
        for (int j = 0; j < 4; ++j) acc[i][j] = (v4i)0;

    __syncthreads();   // drain stage 0

#pragma unroll
    for (int s = 0; s < 4; ++s) {
        if (s < 3) {   // prefetch next stage into the other buffer
            char* d = smem + ((s + 1) & 1) * 16384;
#pragma unroll
            for (int u = 0; u < 2; ++u) {
                gload_lds16(Ab + (s + 1) * 8192 + u * 4096 + tid * 16,
                            d + u * 4096 + (w << 10));
                gload_lds16(Bb + (s + 1) * 8192 + u * 4096 + tid * 16,
                            d + 8192 + u * 4096 + (w << 10));
            }
        }
        const char* As_ = smem + (s & 1) * 16384;
        const char* Bs_ = smem + (s & 1) * 16384 + 8192;
        v4i af[4], bf[4];
#pragma unroll
        for (int i = 0; i < 4; ++i)
            af[i] = *(const v4i*)(As_ + (q4 * 128 + mw * 64 + i * 16 + cl) * 16);
#pragma unroll
        for (int j = 0; j < 4; ++j)
            bf[j] = *(const v4i*)(Bs_ + (q4 * 128 + nw * 64 + j * 16 + cl) * 16);
#pragma unroll
        for (int i = 0; i < 4; ++i)
#pragma unroll
            for (int j = 0; j < 4; ++j)
                acc[i][j] = __builtin_amdgcn_mfma_i32_16x16x64_i8(
                    af[i], bf[j], acc[i][j], 0, 0, 0);
        __syncthreads();
    }

    // per-lane row maxes over this wave's 64 cols (integer domain)
    int pm4[4][4];
#pragma unroll
    for (int i = 0; i < 4; ++i) {
        v4i m = acc[i][0];
#pragma unroll
        for (int j = 1; j < 4; ++j) {
            m.x = max(m.x, acc[i][j].x); m.y = max(m.y, acc[i][j].y);
            m.z = max(m.z, acc[i][j].z); m.w = max(m.w, acc[i][j].w);
        }
        pm4[i][0] = m.x; pm4[i][1] = m.y; pm4[i][2] = m.z; pm4[i][3] = m.w;
#pragma unroll
        for (int g = 0; g < 4; ++g)
#pragma unroll
            for (int off = 1; off < 16; off <<= 1)
                pm4[i][g] = max(pm4[i][g], __shfl_xor(pm4[i][g], off));
    }
    if (cl == 0) {
#pragma unroll
        for (int i = 0; i < 4; ++i)
#pragma unroll
            for (int g = 0; g < 4; ++g)
                red2[mw * 64 + i * 16 + q4 * 4 + g][nw] = pm4[i][g];
    }
    __syncthreads();
    if (tid < 128) {
        int bm = max(red2[tid][0], red2[tid][1]);
        atomicMax(&gmax[n0 + tid], bm);
        thL[tid] = bm - MARGIN_INT;
        lcnt[tid] = 0;
    }
    __syncthreads();

    // compact candidate push into LDS, then one global atomicAdd per row
#pragma unroll
    for (int i = 0; i < 4; ++i)
#pragma unroll
        for (int g = 0; g < 4; ++g) {
            int r = mw * 64 + i * 16 + q4 * 4 + g;
            int th = thL[r];
#pragma unroll
            for (int j = 0; j < 4; ++j) {
                int s = acc[i][j][g];
                if (s >= th) {
                    unsigned slot = atomicAdd(&lcnt[r], 1u);
                    if (slot < 8u) {
                        unsigned k = pn * 128 + nw * 64 + j * 16 + cl;
                        lcand[r * 8 + slot] =
                            ((unsigned long long)(unsigned)s << 32) | k;
                    }
                }
            }
        }
    __syncthreads();
    if (tid < 128) {
        unsigned m = lcnt[tid] < 8u ? lcnt[tid] : 8u;
        bases[tid] = atomicAdd(&cnt[n0 + tid], m);
    }
    __syncthreads();
#pragma unroll
    for (int e0 = 0; e0 < 1024; e0 += 256) {
        int e = e0 + tid;
        int r = e >> 3, s2 = e & 7;
        unsigned m = lcnt[r] < 8u ? lcnt[r] : 8u;
        if ((unsigned)s2 < m) {
            unsigned pos = bases[r] + (unsigned)s2;
            if (pos < 128u)
                cand[(unsigned)(n0 + r) * 128u + pos] = lcand[e];
        }
    }
}

// ---------------------------------------------------------------------------
// Exact rescore + finalize: filter candidates vs global int max, then the
// VALIDATED exact fp32 serial-FMA chain; lowest-index ties via packed u64.
__global__ __launch_bounds__(256) void vq_rescore(
        const float* __restrict__ z, const float* __restrict__ cb,
        const float* __restrict__ z2w, const int* __restrict__ gmax,
        const unsigned* __restrict__ cnt, const unsigned long long* __restrict__ cand,
        int* __restrict__ idx, float* __restrict__ out_idx) {
    __shared__ float zs[32][128];
    __shared__ int thrL[128];
    __shared__ unsigned short cntc[128];
    __shared__ unsigned candL[512];    // (r<<13)|k
    __shared__ unsigned blkcnt;
    __shared__ unsigned long long bestL[128];

    const int t = threadIdx.x;
    const int n0 = blockIdx.x * 128;
    const int b = n0 >> 10, hw0 = n0 & 1023;

    if (t < 128) {
        unsigned c = cnt[n0 + t];
        cntc[t] = (unsigned short)(c < 128u ? c : 128u);
        thrL[t] = gmax[n0 + t] - MARGIN_INT;
        bestL[t] = ~0ull;
    }
    if (t == 0) blkcnt = 0;
    __syncthreads();

    {   // filter: 2 threads per row scan its slots
        int r = t >> 1;
        int c = cntc[r];
        for (int s = (t & 1); s < c; s += 2) {
            unsigned long long e = cand[(unsigned)(n0 + r) * 128u + s];
            int si = (int)(unsigned)(e >> 32);
            if (si >= thrL[r]) {
                unsigned pos = atomicAdd(&blkcnt, 1u);
                if (pos < 512u)
                    candL[pos] = ((unsigned)r << 13) | (unsigned)(e & 0x1FFFu);
            }
        }
    }
    __syncthreads();
    int ns = (int)(blkcnt < 512u ? blkcnt : 512u);

    for (int base = 0; base < ns; base += 256) {
        bool active = base + t < ns;
        int r = 0, k = 0;
        if (active) {
            unsigned v = candL[base + t];
            r = v >> 13; k = v & 8191;
        }
        float sacc = 0.f;
        for (int ch = 0; ch < 8; ++ch) {
            __syncthreads();
            {   // stage 32 channels x 128 rows, coalesced
                int rr = t & 127, cc2 = t >> 7;
#pragma unroll
                for (int u = 0; u < 16; ++u) {
                    int cc = u * 2 + cc2;
                    zs[cc][rr] = z[b * 262144 + (ch * 32 + cc) * 1024 + hw0 + rr];
                }
            }
            __syncthreads();
            if (active) {
                const float4* cbp = (const float4*)(cb + k * 256 + ch * 32);
                float4 A0 = cbp[0], A1 = cbp[1], A2 = cbp[2], A3 = cbp[3];
                float4 A4 = cbp[4], A5 = cbp[5], A6 = cbp[6], A7 = cbp[7];
                float Af[32] = {A0.x,A0.y,A0.z,A0.w, A1.x,A1.y,A1.z,A1.w,
                                A2.x,A2.y,A2.z,A2.w, A3.x,A3.y,A3.z,A3.w,
                                A4.x,A4.y,A4.z,A4.w, A5.x,A5.y,A5.z,A5.w,
                                A6.x,A6.y,A6.z,A6.w, A7.x,A7.y,A7.z,A7.w};
#pragma unroll
                for (int u = 0; u < 32; ++u)
                    sacc = __builtin_fmaf(zs[u][r], Af[u], sacc);
            }
        }
        if (active) {
            float d = z2w[n0 + r] - 2.0f * sacc;   // single rounding, d > 0
            unsigned long long key =
                ((unsigned long long)__float_as_uint(d) << 32) | (unsigned)k;
            atomicMin(&bestL[r], key);
        }
    }
    __syncthreads();
    if (t < 128) {
        int k = (int)(unsigned)(bestL[t] & 0xFFFFFFFFu);
        idx[n0 + t] = k;
        out_idx[n0 + t] = (float)k;
    }
}

// ---------------------------------------------------------------------------
// Scatter + loss, block = (b, i). z staged via LDS transpose (coalesced reads),
// out writes coalesced. out[b,i,j,k] = cb[idx[b*1024+j*32+(k>>3)]][(k&7)*32+i].
__global__ __launch_bounds__(256) void vq_scatter_loss(
        const float* __restrict__ z, const float* __restrict__ cb,
        const int* __restrict__ idx, float* __restrict__ out,
        float* __restrict__ loss_out) {
    __shared__ float zs2[256][33];
    __shared__ int idxs[1024];
    __shared__ float wsum[4];

    const int t = threadIdx.x;
    const int b = blockIdx.x >> 5, i = blockIdx.x & 31;

#pragma unroll
    for (int it = 0; it < 32; ++it) {
        int k = it * 8 + (t >> 5);
        zs2[k][t & 31] = z[b * 262144 + k * 1024 + i * 32 + (t & 31)];
    }
#pragma unroll
    for (int u = 0; u < 4; ++u)
        idxs[u * 256 + t] = idx[b * 1024 + u * 256 + t];
    __syncthreads();

    float lsum = 0.f;
    float* obase = out + b * 262144 + i * 8192;
#pragma unroll 4
    for (int j = 0; j < 32; ++j) {
        int e = idxs[j * 32 + (t >> 3)];
        float zq = cb[e * 256 + (t & 7) * 32 + i];
        float zp = zs2[t][j];
        obase[j * 256 + t] = zq;
        float d = zp - zq;
        lsum = __builtin_fmaf(d, d, lsum);
    }
#pragma unroll
    for (int off = 32; off >= 1; off >>= 1) lsum += __shfl_down(lsum, off, 64);
    int lane = t & 63, wv = t >> 6;
    if (lane == 0) wsum[wv] = lsum;
    __syncthreads();
    if (t == 0)
        atomicAdd(loss_out, (wsum[0] + wsum[1] + wsum[2] + wsum[3]) *
                            (1.25f / (float)NELEM));
}

// ---------------------------------------------------------------------------
extern "C" void kernel_launch(void* const* d_in, const int* in_sizes, int n_in,
                              void* d_out, int out_size, void* d_ws, size_t ws_size,
                              hipStream_t stream) {
    const float* z  = (const float*)d_in[0];
    const float* cb = (const float*)d_in[1];
    float* out = (float*)d_out;

    char* ws = (char*)d_ws;
    char* zbi8             = ws;                              // 4 MB
    char* cbbi8            = ws + 4194304;                    // 2 MB
    unsigned long long* cand = (unsigned long long*)(ws + 6291456);  // 16 MB
    float* z2w             = (float*)(ws + 23068672);
    int*   idx             = (int*)(ws + 23134208);
    int*   gmax            = (int*)(ws + 23199744);
    unsigned* cnt          = (unsigned*)(ws + 23265280);

    vq_prep<<<320, 128, 0, stream>>>(z, cb, z2w, zbi8, cbbi8,
                                     gmax, cnt, out + NELEM);

    vq_gemm<<<8192, 256, 0, stream>>>(zbi8, cbbi8, gmax, cnt, cand);

    vq_rescore<<<NROWS / 128, 256, 0, stream>>>(z, cb, z2w, gmax, cnt, cand,
                                                idx, out + NELEM + 1);

    vq_scatter_loss<<<512, 256, 0, stream>>>(z, cb, idx, out, out + NELEM);
}

// Round 9
// 221.905 us; speedup vs baseline: 4.9158x; 1.0424x over previous
//
#include <hip/hip_runtime.h>
#include <stdint.h>

// Problem constants
#define NROWS 16384   // B*H*W = 16*32*32
#define KENT  8192    // codebook entries
#define CDIM  256     // embedding dim
#define NELEM 4194304 // B*H*W*C elements of z / z_q

// int8 screen scales: z*22 (clamp +-127 = 5.77 sigma), cb*127*8192 (<=0.5 LSB)
#define ZSCALE 22.0f
#define ESCALE 1040384.0f      // 127*8192, exact in fp32
#define MARGIN_INT 4096        // = 1.79e-4 real ~ 8 sigma of i8-quant error

// ws layout (bytes), total 23,330,816 (~22.25 MiB):
//   [0,        4194304): zbi8  i8[4M]   z int8, k-major tile layout
//   [4194304,  6291456): cbi8  i8[2M]   codebook int8, same layout
//   [6291456, 23068672): cand  u64[16384][128]  (score_int<<32 | k)
//   [23068672,23134208): z2w   float[16384]  np-tree row norms
//   [23134208,23199744): idx   int[16384]
//   [23199744,23265280): gmax  i32[16384] row max score  -- init INT_MIN by prep
//   [23265280,23330816): cnt   u32[16384] candidate counts -- zeroed by prep

typedef int v4i __attribute__((ext_vector_type(4)));

__device__ inline int q8(float x, float s) {
    int v = __float2int_rn(x * s);
    return v < -127 ? -127 : (v > 127 ? 127 : v);
}
__device__ inline unsigned pk4(int a, int b, int c, int d) {
    return (a & 255) | ((b & 255) << 8) | ((c & 255) << 16) | ((d & 255) << 24);
}
__device__ inline void gload_lds16(const void* g, void* l) {
    __builtin_amdgcn_global_load_lds(
        (const __attribute__((address_space(1))) void*)g,
        (__attribute__((address_space(3))) void*)l, 16, 0, 0);
}

// ---------------------------------------------------------------------------
// Fused prep: blocks 0..255 = prep_z (VALIDATED np-tree z2 + i8 tile store),
// blocks 256..319 = prep_cb (i8), plus gmax/cnt/loss init.
__global__ __launch_bounds__(128) void vq_prep(
        const float* __restrict__ z, const float* __restrict__ cb,
        float* __restrict__ z2w, char* __restrict__ zbi8,
        char* __restrict__ cbbi8,
        int* __restrict__ gmax, unsigned* __restrict__ cnt,
        float* __restrict__ loss_out) {
    const int t = threadIdx.x;
    const int bid = blockIdx.x;

    if (bid >= 256) {   // ---- prep_cb: panel p, one codebook row per thread
        const int p = bid - 256, n0 = p * 128;
        char* dst = cbbi8 + p * 32768;
        const float* src = cb + (n0 + t) * 256;
#pragma unroll
        for (int q = 0; q < 16; ++q) {
            float4 a = *(const float4*)(src + q * 16);
            float4 b = *(const float4*)(src + q * 16 + 4);
            float4 c = *(const float4*)(src + q * 16 + 8);
            float4 d = *(const float4*)(src + q * 16 + 12);
            uint4 v;
            v.x = pk4(q8(a.x,ESCALE), q8(a.y,ESCALE), q8(a.z,ESCALE), q8(a.w,ESCALE));
            v.y = pk4(q8(b.x,ESCALE), q8(b.y,ESCALE), q8(b.z,ESCALE), q8(b.w,ESCALE));
            v.z = pk4(q8(c.x,ESCALE), q8(c.y,ESCALE), q8(c.z,ESCALE), q8(c.w,ESCALE));
            v.w = pk4(q8(d.x,ESCALE), q8(d.y,ESCALE), q8(d.z,ESCALE), q8(d.w,ESCALE));
            *(uint4*)&dst[(q * 128 + t) * 16] = v;
        }
        if (p == 0 && t == 0) loss_out[0] = 0.f;
        return;
    }

    // ---- prep_z: 2 threads/row, one per 128-c half of the np tree
    __shared__ float s64[64];
    const int r = t & 63;
    const int blk = t >> 6;
    const int n = bid * 64 + r;
    const int b = n >> 10, hw = n & 1023;
    const float* base = z + b * 262144 + hw;

    if (blk == 0) gmax[bid * 64 + r] = (int)0x80000000;   // INT_MIN
    else          cnt[bid * 64 + r] = 0u;

    const int p = n >> 7, rp = n & 127;
    char* dst = zbi8 + p * 32768;

    float t0[16], p01[16], p0123[16], C[16];

#pragma unroll
    for (int j = 0; j < 8; ++j) {
        float a[16];
#pragma unroll
        for (int L = 0; L < 16; ++L)
            a[L] = base[(blk * 128 + L + 16 * j) * 1024];
        int qb[16];
#pragma unroll
        for (int L = 0; L < 16; ++L) {
            qb[L] = q8(a[L], ZSCALE);
            float sq = a[L] * a[L];
            asm volatile("" : "+v"(sq));   // forbid FMA contraction into adds
            // np tree phases: C = ((q0+q1)+(q2+q3)) + ((q4+q5)+(q6+q7))
            if (j == 0 || j == 2 || j == 4 || j == 6) t0[L] = sq;
            else if (j == 1) p01[L] = t0[L] + sq;
            else if (j == 3) p0123[L] = p01[L] + (t0[L] + sq);
            else if (j == 5) p01[L] = t0[L] + sq;                 // p45
            else             C[L] = p0123[L] + (p01[L] + (t0[L] + sq));
        }
        uint4 v;
        v.x = pk4(qb[0], qb[1], qb[2], qb[3]);
        v.y = pk4(qb[4], qb[5], qb[6], qb[7]);
        v.z = pk4(qb[8], qb[9], qb[10], qb[11]);
        v.w = pk4(qb[12], qb[13], qb[14], qb[15]);
        *(uint4*)&dst[((blk * 8 + j) * 128 + rp) * 16] = v;
    }
    float t8[8];
#pragma unroll
    for (int L = 0; L < 8; ++L) t8[L] = C[L] + C[L + 8];
    float t4[4];
#pragma unroll
    for (int L = 0; L < 4; ++L) t4[L] = t8[L] + t8[L + 4];
    float t2a = t4[0] + t4[2];
    float t2b = t4[1] + t4[3];
    float bs = t2a + t2b;

    if (blk == 1) s64[r] = bs;
    __syncthreads();
    if (blk == 0) z2w[n] = bs + s64[r];
}

// ---------------------------------------------------------------------------
// int8 MFMA screen v5: whole A panel (32KB i8) in LDS, ONE staging drain;
// B fragments streamed straight from L2 (16B/lane contiguous in the k-major
// layout), prefetched one K-step ahead. K-loop is barrier-free. 4 blocks/CU.
#define SMEM_AS    0        // 32768 B A panel (aliased by lcand post-loop)
#define SMEM_RED2  32768    // 1024
#define SMEM_THL   33792    // 512
#define SMEM_LCNT  34304    // 512
#define SMEM_BASES 34816    // 512
#define SMEM_SZ    35328

__global__ __launch_bounds__(256, 4) void vq_gemm(
        const char* __restrict__ zbi8,
        const char* __restrict__ cbbi8,
        int* __restrict__ gmax, unsigned* __restrict__ cnt,
        unsigned long long* __restrict__ cand) {
    __shared__ __align__(16) char smem[SMEM_SZ];
    int (*red2)[2] = (int(*)[2])(smem + SMEM_RED2);
    int* thL = (int*)(smem + SMEM_THL);
    unsigned* lcnt = (unsigned*)(smem + SMEM_LCNT);
    unsigned* bases = (unsigned*)(smem + SMEM_BASES);
    unsigned long long* lcand = (unsigned long long*)smem;  // aliases A panel

    const int tid = threadIdx.x;
    const int w = tid >> 6, l = tid & 63;
    const int q4 = l >> 4, cl = l & 15;
    const int mw = w & 1, nw = w >> 1;

    // XCD-locality swizzle (validated r5): 16 pm x phased 16 pn per XCD
    const unsigned bx = blockIdx.x;
    const unsigned xcd = bx & 7, local = bx >> 3;
    const unsigned png = local >> 8;
    const unsigned rem = local & 255;
    const unsigned pm = (rem >> 4) * 8 + xcd;
    const unsigned pn = png * 16 + (rem & 15);
    const int n0 = pm * 128;

    const char* Ab = zbi8 + pm * 32768;
    const char* Bb = cbbi8 + pn * 32768;

    // stage whole A panel: 8 issues x 256 thr x 16B = 32KB
#pragma unroll
    for (int u = 0; u < 8; ++u)
        gload_lds16(Ab + u * 4096 + tid * 16, smem + u * 4096 + (w << 10));

    // B: per-lane contiguous 16B fragments from L2; j via imm offset, kt via +8192
    const char* bbase = Bb + (q4 * 128 + nw * 64 + cl) * 16;
    v4i bf[4], bfn[4];
#pragma unroll
    for (int j = 0; j < 4; ++j)
        bf[j] = *(const v4i*)(bbase + j * 256);

    v4i acc[4][4];
#pragma unroll
    for (int i = 0; i < 4; ++i)
#pragma unroll
        for (int j = 0; j < 4; ++j) acc[i][j] = (v4i)0;

    __syncthreads();   // single A-staging drain (bf loads ride along)

#pragma unroll
    for (int kt = 0; kt < 4; ++kt) {
        v4i af[4];
#pragma unroll
        for (int i = 0; i < 4; ++i)
            af[i] = *(const v4i*)(smem +
                ((kt * 4 + q4) * 128 + mw * 64 + i * 16 + cl) * 16);
        if (kt < 3) {
#pragma unroll
            for (int j = 0; j < 4; ++j)
                bfn[j] = *(const v4i*)(bbase + (kt + 1) * 8192 + j * 256);
        }
#pragma unroll
        for (int i = 0; i < 4; ++i)
#pragma unroll
            for (int j = 0; j < 4; ++j)
                acc[i][j] = __builtin_amdgcn_mfma_i32_16x16x64_i8(
                    af[i], bf[j], acc[i][j], 0, 0, 0);
#pragma unroll
        for (int j = 0; j < 4; ++j) bf[j] = bfn[j];
    }

    // per-lane row maxes over this wave's 64 cols (integer domain)
    int pm4[4][4];
#pragma unroll
    for (int i = 0; i < 4; ++i) {
        v4i m = acc[i][0];
#pragma unroll
        for (int j = 1; j < 4; ++j) {
            m.x = max(m.x, acc[i][j].x); m.y = max(m.y, acc[i][j].y);
            m.z = max(m.z, acc[i][j].z); m.w = max(m.w, acc[i][j].w);
        }
        pm4[i][0] = m.x; pm4[i][1] = m.y; pm4[i][2] = m.z; pm4[i][3] = m.w;
#pragma unroll
        for (int g = 0; g < 4; ++g)
#pragma unroll
            for (int off = 1; off < 16; off <<= 1)
                pm4[i][g] = max(pm4[i][g], __shfl_xor(pm4[i][g], off));
    }
    if (cl == 0) {
#pragma unroll
        for (int i = 0; i < 4; ++i)
#pragma unroll
            for (int g = 0; g < 4; ++g)
                red2[mw * 64 + i * 16 + q4 * 4 + g][nw] = pm4[i][g];
    }
    __syncthreads();
    if (tid < 128) {
        int bm = max(red2[tid][0], red2[tid][1]);
        atomicMax(&gmax[n0 + tid], bm);
        thL[tid] = bm - MARGIN_INT;
        lcnt[tid] = 0;
    }
    __syncthreads();

    // candidate push: wave-max pre-check per (i,g), then detailed 4-j scan
#pragma unroll
    for (int i = 0; i < 4; ++i)
#pragma unroll
        for (int g = 0; g < 4; ++g) {
            int r = mw * 64 + i * 16 + q4 * 4 + g;
            int th = thL[r];
            if (pm4[i][g] >= th) {
#pragma unroll
                for (int j = 0; j < 4; ++j) {
                    int s = acc[i][j][g];
                    if (s >= th) {
                        unsigned slot = atomicAdd(&lcnt[r], 1u);
                        if (slot < 8u) {
                            unsigned k = pn * 128 + nw * 64 + j * 16 + cl;
                            lcand[r * 8 + slot] =
                                ((unsigned long long)(unsigned)s << 32) | k;
                        }
                    }
                }
            }
        }
    __syncthreads();
    if (tid < 128) {
        unsigned m = lcnt[tid] < 8u ? lcnt[tid] : 8u;
        bases[tid] = atomicAdd(&cnt[n0 + tid], m);
    }
    __syncthreads();
#pragma unroll
    for (int e0 = 0; e0 < 1024; e0 += 256) {
        int e = e0 + tid;
        int r = e >> 3, s2 = e & 7;
        unsigned m = lcnt[r] < 8u ? lcnt[r] : 8u;
        if ((unsigned)s2 < m) {
            unsigned pos = bases[r] + (unsigned)s2;
            if (pos < 128u)
                cand[(unsigned)(n0 + r) * 128u + pos] = lcand[e];
        }
    }
}

// ---------------------------------------------------------------------------
// Exact rescore + finalize: filter candidates vs global int max, then the
// VALIDATED exact fp32 serial-FMA chain; lowest-index ties via packed u64.
__global__ __launch_bounds__(256) void vq_rescore(
        const float* __restrict__ z, const float* __restrict__ cb,
        const float* __restrict__ z2w, const int* __restrict__ gmax,
        const unsigned* __restrict__ cnt, const unsigned long long* __restrict__ cand,
        int* __restrict__ idx, float* __restrict__ out_idx) {
    __shared__ float zs[32][128];
    __shared__ int thrL[128];
    __shared__ unsigned short cntc[128];
    __shared__ unsigned candL[512];    // (r<<13)|k
    __shared__ unsigned blkcnt;
    __shared__ unsigned long long bestL[128];

    const int t = threadIdx.x;
    const int n0 = blockIdx.x * 128;
    const int b = n0 >> 10, hw0 = n0 & 1023;

    if (t < 128) {
        unsigned c = cnt[n0 + t];
        cntc[t] = (unsigned short)(c < 128u ? c : 128u);
        thrL[t] = gmax[n0 + t] - MARGIN_INT;
        bestL[t] = ~0ull;
    }
    if (t == 0) blkcnt = 0;
    __syncthreads();

    {   // filter: 2 threads per row scan its slots
        int r = t >> 1;
        int c = cntc[r];
        for (int s = (t & 1); s < c; s += 2) {
            unsigned long long e = cand[(unsigned)(n0 + r) * 128u + s];
            int si = (int)(unsigned)(e >> 32);
            if (si >= thrL[r]) {
                unsigned pos = atomicAdd(&blkcnt, 1u);
                if (pos < 512u)
                    candL[pos] = ((unsigned)r << 13) | (unsigned)(e & 0x1FFFu);
            }
        }
    }
    __syncthreads();
    int ns = (int)(blkcnt < 512u ? blkcnt : 512u);

    for (int base = 0; base < ns; base += 256) {
        bool active = base + t < ns;
        int r = 0, k = 0;
        if (active) {
            unsigned v = candL[base + t];
            r = v >> 13; k = v & 8191;
        }
        float sacc = 0.f;
        for (int ch = 0; ch < 8; ++ch) {
            __syncthreads();
            {   // stage 32 channels x 128 rows, coalesced
                int rr = t & 127, cc2 = t >> 7;
#pragma unroll
                for (int u = 0; u < 16; ++u) {
                    int cc = u * 2 + cc2;
                    zs[cc][rr] = z[b * 262144 + (ch * 32 + cc) * 1024 + hw0 + rr];
                }
            }
            __syncthreads();
            if (active) {
                const float4* cbp = (const float4*)(cb + k * 256 + ch * 32);
                float4 A0 = cbp[0], A1 = cbp[1], A2 = cbp[2], A3 = cbp[3];
                float4 A4 = cbp[4], A5 = cbp[5], A6 = cbp[6], A7 = cbp[7];
                float Af[32] = {A0.x,A0.y,A0.z,A0.w, A1.x,A1.y,A1.z,A1.w,
                                A2.x,A2.y,A2.z,A2.w, A3.x,A3.y,A3.z,A3.w,
                                A4.x,A4.y,A4.z,A4.w, A5.x,A5.y,A5.z,A5.w,
                                A6.x,A6.y,A6.z,A6.w, A7.x,A7.y,A7.z,A7.w};
#pragma unroll
                for (int u = 0; u < 32; ++u)
                    sacc = __builtin_fmaf(zs[u][r], Af[u], sacc);
            }
        }
        if (active) {
            float d = z2w[n0 + r] - 2.0f * sacc;   // single rounding, d > 0
            unsigned long long key =
                ((unsigned long long)__float_as_uint(d) << 32) | (unsigned)k;
            atomicMin(&bestL[r], key);
        }
    }
    __syncthreads();
    if (t < 128) {
        int k = (int)(unsigned)(bestL[t] & 0xFFFFFFFFu);
        idx[n0 + t] = k;
        out_idx[n0 + t] = (float)k;
    }
}

// ---------------------------------------------------------------------------
// Scatter v2, block = (b, j): cb rows gathered ROW-CONTIGUOUSLY (no 16x
// over-fetch) into an LDS tile, out written k-coalesced via LDS transpose.
// out[b,i,j,k] = cb[idx[b*1024+j*32+(k>>3)]][(k&7)*32+i]. No z, no loss here.
__global__ __launch_bounds__(256) void vq_scatter_out(
        const float* __restrict__ cb, const int* __restrict__ idx,
        float* __restrict__ out) {
    __shared__ float tile[32 * 257];   // [w][c], stride 257 floats
    __shared__ int idxs[32];

    const int t = threadIdx.x;
    const int b = blockIdx.x >> 5, j = blockIdx.x & 31;

    if (t < 32) idxs[t] = idx[b * 1024 + j * 32 + t];
    __syncthreads();

    {   // stage: wave reads 64 consecutive c of one cb row (coalesced)
        const int c0 = t & 63;
        const int w0 = (t >> 6) * 8;
#pragma unroll
        for (int it = 0; it < 8; ++it) {
            int w = w0 + it;
            const float* src = cb + idxs[w] * 256 + c0;
            float* drow = tile + w * 257 + c0;
            drow[0]   = src[0];
            drow[64]  = src[64];
            drow[128] = src[128];
            drow[192] = src[192];
        }
    }
    __syncthreads();

    float* obase = out + b * 262144 + j * 256;
    const int wv = t >> 3, cb8 = (t & 7) * 32;
#pragma unroll
    for (int it = 0; it < 32; ++it)     // it = i; lane = k (coalesced store)
        obase[it * 8192 + t] = tile[wv * 257 + cb8 + it];
}

// ---------------------------------------------------------------------------
// Loss, block = (b, i): z read w-coalesced (staged), out re-read coalesced.
// loss += 1.25/N * sum((zp - zq)^2);  zp(o) = z[b,k,i,j], zq(o) = out[o].
__global__ __launch_bounds__(256) void vq_loss(
        const float* __restrict__ z, const float* __restrict__ out,
        float* __restrict__ loss_out) {
    __shared__ float zs[256][33];
    __shared__ float wsum[4];

    const int t = threadIdx.x;
    const int b = blockIdx.x >> 5, i = blockIdx.x & 31;

#pragma unroll
    for (int it = 0; it < 32; ++it) {
        int k = it * 8 + (t >> 5);
        zs[k][t & 31] = z[b * 262144 + k * 1024 + i * 32 + (t & 31)];
    }
    __syncthreads();

    const float* ob = out + b * 262144 + i * 8192;
    float lsum = 0.f;
#pragma unroll 4
    for (int it = 0; it < 32; ++it) {   // it = j; lane = k
        float d = zs[t][it] - ob[it * 256 + t];
        lsum = __builtin_fmaf(d, d, lsum);
    }
#pragma unroll
    for (int off = 32; off >= 1; off >>= 1) lsum += __shfl_down(lsum, off, 64);
    int lane = t & 63, wv = t >> 6;
    if (lane == 0) wsum[wv] = lsum;
    __syncthreads();
    if (t == 0)
        atomicAdd(loss_out, (wsum[0] + wsum[1] + wsum[2] + wsum[3]) *
                            (1.25f / (float)NELEM));
}

// ---------------------------------------------------------------------------
extern "C" void kernel_launch(void* const* d_in, const int* in_sizes, int n_in,
                              void* d_out, int out_size, void* d_ws, size_t ws_size,
                              hipStream_t stream) {
    const float* z  = (const float*)d_in[0];
    const float* cb = (const float*)d_in[1];
    float* out = (float*)d_out;

    char* ws = (char*)d_ws;
    char* zbi8             = ws;                              // 4 MB
    char* cbbi8            = ws + 4194304;                    // 2 MB
    unsigned long long* cand = (unsigned long long*)(ws + 6291456);  // 16 MB
    float* z2w             = (float*)(ws + 23068672);
    int*   idx             = (int*)(ws + 23134208);
    int*   gmax            = (int*)(ws + 23199744);
    unsigned* cnt          = (unsigned*)(ws + 23265280);

    vq_prep<<<320, 128, 0, stream>>>(z, cb, z2w, zbi8, cbbi8,
                                     gmax, cnt, out + NELEM);

    vq_gemm<<<8192, 256, 0, stream>>>(zbi8, cbbi8, gmax, cnt, cand);

    vq_rescore<<<NROWS / 128, 256, 0, stream>>>(z, cb, z2w, gmax, cnt, cand,
                                                idx, out + NELEM + 1);

    vq_scatter_out<<<512, 256, 0, stream>>>(cb, idx, out);

    vq_loss<<<512, 256, 0, stream>>>(z, out, out + NELEM);
}